// Round 8
// baseline (287.862 us; speedup 1.0000x reference)
//
#include <hip/hip_runtime.h>

#define NN 50000
#define NE 800000
#define NG 256
#define NB ((NN + 255) / 256)   // scan blocks
#define N4 (NN * 128 / 4)       // float4 count of x (1.6M)
#define NQ (NE / 4)             // edge quads (200000)

typedef __attribute__((ext_vector_type(8))) short bf16x8;
typedef __attribute__((ext_vector_type(4))) float f32x4;

// ---------- bf16 helpers ----------
__device__ __forceinline__ unsigned short f2bf_rne(float f) {
    unsigned u = __float_as_uint(f);
    u += 0x7fffu + ((u >> 16) & 1u);   // round-to-nearest-even
    return (unsigned short)(u >> 16);
}
#define BF2F_LO(u) __uint_as_float((u) << 16)
#define BF2F_HI(u) __uint_as_float((u) & 0xffff0000u)

// ---------- merged: x->bf16 convert + degree histogram (deg pre-zeroed) ----------
// 32 edge-quads per block, spread over all 4 waves (lanes 0-7 each): 4 independent
// returning atomics per lane, atomic tail shared by 4 waves per block.
__global__ void conv_hist(const float4* __restrict__ x, ushort4* __restrict__ xh,
                          const int4* __restrict__ dst4, int* __restrict__ deg,
                          int4* __restrict__ eoff4) {
    int i = blockIdx.x * 256 + threadIdx.x;
    if (i < N4) {
        float4 v = x[i];
        ushort4 o;
        o.x = f2bf_rne(v.x); o.y = f2bf_rne(v.y);
        o.z = f2bf_rne(v.z); o.w = f2bf_rne(v.w);
        xh[i] = o;
    }
    int wv = threadIdx.x >> 6, ln = threadIdx.x & 63;
    if (ln < 8) {
        int q = blockIdx.x * 32 + wv * 8 + ln;   // 6250 blocks * 32 = NQ exactly
        if (q < NQ) {
            int4 d = dst4[q];
            int o0 = atomicAdd(&deg[d.x], 1);
            int o1 = atomicAdd(&deg[d.y], 1);
            int o2 = atomicAdd(&deg[d.z], 1);
            int o3 = atomicAdd(&deg[d.w], 1);
            eoff4[q] = make_int4(o0, o1, o2, o3);
        }
    }
}

// ---------- CSR scan (+ weight transpose/convert for MFMA gemms) ----------
__global__ void block_scan(const int* __restrict__ deg, int* __restrict__ iscan,
                           int* __restrict__ bsum,
                           const float* __restrict__ W1, const float* __restrict__ W2,
                           const float* __restrict__ W3,
                           const float* __restrict__ W21, const float* __restrict__ W12,
                           unsigned short* __restrict__ W1t,
                           unsigned short* __restrict__ W2t,
                           unsigned short* __restrict__ W3t,
                           unsigned short* __restrict__ W21t,
                           unsigned short* __restrict__ W12t) {
    // weight prep: Wt[n][k] = bf16(W[k][n]) (independent side-work)
    int gidx = blockIdx.x * 256 + threadIdx.x;
    if (gidx < 16384) {
        int n = gidx >> 7, k = gidx & 127;
        W1t[gidx] = f2bf_rne(W1[k * 128 + n]);
        W2t[gidx] = f2bf_rne(W2[k * 128 + n]);
    } else if (gidx < 24576) {
        int i2 = gidx - 16384;
        int n = i2 >> 7, k = i2 & 127;      // n in [0,64), k in [0,128)
        W3t[i2] = f2bf_rne(W3[k * 64 + n]);
    } else if (gidx < 28672) {
        int i3 = gidx - 24576;
        int n = i3 >> 6, k = i3 & 63;       // 64x64
        W21t[i3] = f2bf_rne(W21[k * 64 + n]);
    } else if (gidx < 30720) {
        int i4 = gidx - 28672;
        int n = i4 >> 6, k = i4 & 63;       // n in [0,32), k in [0,64)
        W12t[i4] = f2bf_rne(W12[k * 32 + n]);
    }

    __shared__ int sh[256];
    int t = threadIdx.x;
    int i = blockIdx.x * 256 + t;
    int v = (i < NN) ? deg[i] : 0;
    sh[t] = v;
    __syncthreads();
    #pragma unroll
    for (int off = 1; off < 256; off <<= 1) {
        int add = (t >= off) ? sh[t - off] : 0;
        __syncthreads();
        sh[t] += add;
        __syncthreads();
    }
    if (i < NN) iscan[i] = sh[t];
    if (t == 255) bsum[blockIdx.x] = sh[255];
}

__global__ void scan_bsum(const int* __restrict__ bsum, int* __restrict__ boff) {
    __shared__ int sh[256];
    int t = threadIdx.x;
    int v = (t < NB) ? bsum[t] : 0;
    sh[t] = v;
    __syncthreads();
    #pragma unroll
    for (int off = 1; off < 256; off <<= 1) {
        int add = (t >= off) ? sh[t - off] : 0;
        __syncthreads();
        sh[t] += add;
        __syncthreads();
    }
    if (t < NB) boff[t] = sh[t] - v;  // exclusive
}

// merged: rowptr finalize + graph-bounds (batch is sorted)
__global__ void finalize_bounds(const int* __restrict__ deg, const int* __restrict__ iscan,
                                const int* __restrict__ boff, int* __restrict__ rowptr,
                                const int* __restrict__ batch, int* __restrict__ gstart) {
    int i = blockIdx.x * 256 + threadIdx.x;
    if (i < NN) {
        rowptr[i] = iscan[i] - deg[i] + boff[blockIdx.x];
        int b = batch[i];
        if (i == 0) {
            for (int g = 0; g <= b; g++) gstart[g] = 0;
        } else {
            int p = batch[i - 1];
            for (int g = p + 1; g <= b; g++) gstart[g] = i;
        }
        if (i == NN - 1) {
            for (int g = b + 1; g <= NG; g++) gstart[g] = NN;
        }
    }
    if (i == 0) rowptr[NN] = NE;
}

// 4 edges per thread: int4 loads, 4 independent rowptr gathers + scatters
__global__ void fill_csr2(const int4* __restrict__ src4, const int4* __restrict__ dst4,
                          const int* __restrict__ rowptr, const int4* __restrict__ eoff4,
                          int* __restrict__ esrc) {
    int q = blockIdx.x * 256 + threadIdx.x;
    if (q >= NQ) return;
    int4 s = src4[q];
    int4 d = dst4[q];
    int4 o = eoff4[q];
    int r0 = rowptr[d.x];
    int r1 = rowptr[d.y];
    int r2 = rowptr[d.z];
    int r3 = rowptr[d.w];
    esrc[r0 + o.x] = s.x;
    esrc[r1 + o.y] = s.y;
    esrc[r2 + o.z] = s.z;
    esrc[r3 + o.w] = s.w;
}

// ---------- bf16 wave-cooperative gathers ----------
// C lane-chunks per row, EPI = 64/C edges per pass; 4x/2x/1x unroll keeps
// up to 4 independent loads in flight.

// 16B-lane variant (rows = 256B): x (128 cols)
template <int C4>
__device__ __forceinline__ void gather_bf16(const uint4* __restrict__ x4,
                                            const int* __restrict__ esrc,
                                            int beg, int cnt, int node, int lane,
                                            float* a /* [8] */) {
    constexpr int EPI = 64 / C4;
    const int chunk = lane & (C4 - 1);
    const int esl   = lane / C4;
    #define ACC_U4(u) do { \
        a[0] += BF2F_LO((u).x); a[1] += BF2F_HI((u).x); \
        a[2] += BF2F_LO((u).y); a[3] += BF2F_HI((u).y); \
        a[4] += BF2F_LO((u).z); a[5] += BF2F_HI((u).z); \
        a[6] += BF2F_LO((u).w); a[7] += BF2F_HI((u).w); } while (0)
    if (esl == 0) { uint4 u = x4[(size_t)node * C4 + chunk]; ACC_U4(u); }
    for (int c = 0; c < cnt; c += 64) {
        int take = min(64, cnt - c);
        int myi = (lane < take) ? esrc[beg + c + lane] : 0;
        int i = 0;
        for (; i + 4 * EPI <= take; i += 4 * EPI) {
            int s0 = __shfl(myi, i + esl);
            int s1 = __shfl(myi, i + EPI + esl);
            int s2 = __shfl(myi, i + 2 * EPI + esl);
            int s3 = __shfl(myi, i + 3 * EPI + esl);
            uint4 u0 = x4[(size_t)s0 * C4 + chunk];
            uint4 u1 = x4[(size_t)s1 * C4 + chunk];
            uint4 u2 = x4[(size_t)s2 * C4 + chunk];
            uint4 u3 = x4[(size_t)s3 * C4 + chunk];
            ACC_U4(u0); ACC_U4(u1); ACC_U4(u2); ACC_U4(u3);
        }
        if (i + 2 * EPI <= take) {
            int s0 = __shfl(myi, i + esl);
            int s1 = __shfl(myi, i + EPI + esl);
            uint4 u0 = x4[(size_t)s0 * C4 + chunk];
            uint4 u1 = x4[(size_t)s1 * C4 + chunk];
            ACC_U4(u0); ACC_U4(u1);
            i += 2 * EPI;
        }
        if (i + EPI <= take) {
            int s = __shfl(myi, i + esl);
            uint4 u = x4[(size_t)s * C4 + chunk];
            ACC_U4(u);
            i += EPI;
        }
        int rem = take - i;
        if (rem > 0) {
            int s = __shfl(myi, i + ((esl < rem) ? esl : 0));
            uint4 u = x4[(size_t)s * C4 + chunk];
            if (esl < rem) ACC_U4(u);
        }
    }
    #undef ACC_U4
    for (int off = 32; off >= C4; off >>= 1) {
        #pragma unroll
        for (int q = 0; q < 8; q++)
            a[q] += __shfl_xor(a[q], off);
    }
}

// 8B-lane variant (rows = 128B): z1 (64 cols). C=16, EPI=4.
template <int C>
__device__ __forceinline__ void gather_bf16_u2(const uint2* __restrict__ x2,
                                               const int* __restrict__ esrc,
                                               int beg, int cnt, int node, int lane,
                                               float* a /* [4] */) {
    constexpr int EPI = 64 / C;
    const int chunk = lane & (C - 1);
    const int esl   = lane / C;
    #define ACC_U2(u) do { \
        a[0] += BF2F_LO((u).x); a[1] += BF2F_HI((u).x); \
        a[2] += BF2F_LO((u).y); a[3] += BF2F_HI((u).y); } while (0)
    if (esl == 0) { uint2 u = x2[(size_t)node * C + chunk]; ACC_U2(u); }
    for (int c = 0; c < cnt; c += 64) {
        int take = min(64, cnt - c);
        int myi = (lane < take) ? esrc[beg + c + lane] : 0;
        int i = 0;
        for (; i + 4 * EPI <= take; i += 4 * EPI) {
            int s0 = __shfl(myi, i + esl);
            int s1 = __shfl(myi, i + EPI + esl);
            int s2 = __shfl(myi, i + 2 * EPI + esl);
            int s3 = __shfl(myi, i + 3 * EPI + esl);
            uint2 u0 = x2[(size_t)s0 * C + chunk];
            uint2 u1 = x2[(size_t)s1 * C + chunk];
            uint2 u2 = x2[(size_t)s2 * C + chunk];
            uint2 u3 = x2[(size_t)s3 * C + chunk];
            ACC_U2(u0); ACC_U2(u1); ACC_U2(u2); ACC_U2(u3);
        }
        if (i + 2 * EPI <= take) {
            int s0 = __shfl(myi, i + esl);
            int s1 = __shfl(myi, i + EPI + esl);
            uint2 u0 = x2[(size_t)s0 * C + chunk];
            uint2 u1 = x2[(size_t)s1 * C + chunk];
            ACC_U2(u0); ACC_U2(u1);
            i += 2 * EPI;
        }
        if (i + EPI <= take) {
            int s = __shfl(myi, i + esl);
            uint2 u = x2[(size_t)s * C + chunk];
            ACC_U2(u);
            i += EPI;
        }
        int rem = take - i;
        if (rem > 0) {
            int s = __shfl(myi, i + ((esl < rem) ? esl : 0));
            uint2 u = x2[(size_t)s * C + chunk];
            if (esl < rem) ACC_U2(u);
        }
    }
    #undef ACC_U2
    for (int off = 32; off >= C; off >>= 1) {
        #pragma unroll
        for (int q = 0; q < 4; q++)
            a[q] += __shfl_xor(a[q], off);
    }
}

// 4B-lane variant (rows = 64B): z2 (32 cols). C=16, EPI=4.
template <int C>
__device__ __forceinline__ void gather_bf16_u1(const unsigned* __restrict__ x1,
                                               const int* __restrict__ esrc,
                                               int beg, int cnt, int node, int lane,
                                               float* a /* [2] */) {
    constexpr int EPI = 64 / C;
    const int chunk = lane & (C - 1);
    const int esl   = lane / C;
    #define ACC_U1(u) do { \
        a[0] += BF2F_LO(u); a[1] += BF2F_HI(u); } while (0)
    if (esl == 0) { unsigned u = x1[(size_t)node * C + chunk]; ACC_U1(u); }
    for (int c = 0; c < cnt; c += 64) {
        int take = min(64, cnt - c);
        int myi = (lane < take) ? esrc[beg + c + lane] : 0;
        int i = 0;
        for (; i + 4 * EPI <= take; i += 4 * EPI) {
            int s0 = __shfl(myi, i + esl);
            int s1 = __shfl(myi, i + EPI + esl);
            int s2 = __shfl(myi, i + 2 * EPI + esl);
            int s3 = __shfl(myi, i + 3 * EPI + esl);
            unsigned u0 = x1[(size_t)s0 * C + chunk];
            unsigned u1 = x1[(size_t)s1 * C + chunk];
            unsigned u2 = x1[(size_t)s2 * C + chunk];
            unsigned u3 = x1[(size_t)s3 * C + chunk];
            ACC_U1(u0); ACC_U1(u1); ACC_U1(u2); ACC_U1(u3);
        }
        if (i + 2 * EPI <= take) {
            int s0 = __shfl(myi, i + esl);
            int s1 = __shfl(myi, i + EPI + esl);
            unsigned u0 = x1[(size_t)s0 * C + chunk];
            unsigned u1 = x1[(size_t)s1 * C + chunk];
            ACC_U1(u0); ACC_U1(u1);
            i += 2 * EPI;
        }
        if (i + EPI <= take) {
            int s = __shfl(myi, i + esl);
            unsigned u = x1[(size_t)s * C + chunk];
            ACC_U1(u);
            i += EPI;
        }
        int rem = take - i;
        if (rem > 0) {
            int s = __shfl(myi, i + ((esl < rem) ? esl : 0));
            unsigned u = x1[(size_t)s * C + chunk];
            if (esl < rem) ACC_U1(u);
        }
    }
    #undef ACC_U1
    for (int off = 32; off >= C; off >>= 1) {
        #pragma unroll
        for (int q = 0; q < 2; q++)
            a[q] += __shfl_xor(a[q], off);
    }
}

// ---------- L0 gather: one wave per node -> bf16 agg ----------
__global__ __launch_bounds__(256) void gather_L0(
        const unsigned short* __restrict__ xh, const int* __restrict__ esrc,
        const int* __restrict__ rowptr, unsigned short* __restrict__ aggh /* N x 128 bf16 */) {
    const int wave = threadIdx.x >> 6, lane = threadIdx.x & 63;
    const int node = blockIdx.x * 4 + wave;
    if (node >= NN) return;
    float a[8] = {0, 0, 0, 0, 0, 0, 0, 0};
    int beg = rowptr[node], end = rowptr[node + 1];
    gather_bf16<16>((const uint4*)xh, esrc, beg, end - beg, node, lane, a);
    if (lane < 16) {
        uint4 o;
        o.x = (unsigned)f2bf_rne(a[0]) | ((unsigned)f2bf_rne(a[1]) << 16);
        o.y = (unsigned)f2bf_rne(a[2]) | ((unsigned)f2bf_rne(a[3]) << 16);
        o.z = (unsigned)f2bf_rne(a[4]) | ((unsigned)f2bf_rne(a[5]) << 16);
        o.w = (unsigned)f2bf_rne(a[6]) | ((unsigned)f2bf_rne(a[7]) << 16);
        *(uint4*)&aggh[(size_t)node * 128 + lane * 8] = o;
    }
}

// ---------- L1 gather: one wave per node; +b1, relu -> bf16 agg1 ----------
__global__ __launch_bounds__(256) void gather_L1(
        const unsigned short* __restrict__ z1h, const int* __restrict__ esrc,
        const int* __restrict__ rowptr, const float* __restrict__ b1,
        unsigned short* __restrict__ agg1h /* N x 64 bf16 */) {
    const int wave = threadIdx.x >> 6, lane = threadIdx.x & 63;
    const int node = blockIdx.x * 4 + wave;
    if (node >= NN) return;
    float a[4] = {0, 0, 0, 0};
    int beg = rowptr[node], end = rowptr[node + 1];
    gather_bf16_u2<16>((const uint2*)z1h, esrc, beg, end - beg, node, lane, a);
    if (lane < 16) {
        float4 bv = *(const float4*)&b1[lane * 4];
        uint2 o;
        o.x = (unsigned)f2bf_rne(fmaxf(a[0] + bv.x, 0.f)) |
              ((unsigned)f2bf_rne(fmaxf(a[1] + bv.y, 0.f)) << 16);
        o.y = (unsigned)f2bf_rne(fmaxf(a[2] + bv.z, 0.f)) |
              ((unsigned)f2bf_rne(fmaxf(a[3] + bv.w, 0.f)) << 16);
        *(uint2*)&agg1h[(size_t)node * 64 + lane * 4] = o;
    }
}

// ---------- L2 gather: one wave per node; +b1, relu -> bf16 agg2 ----------
__global__ __launch_bounds__(256) void gather_L2(
        const unsigned short* __restrict__ z2h, const int* __restrict__ esrc,
        const int* __restrict__ rowptr, const float* __restrict__ b1,
        unsigned short* __restrict__ agg2h /* N x 32 bf16 */) {
    const int wave = threadIdx.x >> 6, lane = threadIdx.x & 63;
    const int node = blockIdx.x * 4 + wave;
    if (node >= NN) return;
    float a[2] = {0, 0};
    int beg = rowptr[node], end = rowptr[node + 1];
    gather_bf16_u1<16>((const unsigned*)z2h, esrc, beg, end - beg, node, lane, a);
    if (lane < 16) {
        float2 bv = *(const float2*)&b1[lane * 2];
        unsigned o = (unsigned)f2bf_rne(fmaxf(a[0] + bv.x, 0.f)) |
                     ((unsigned)f2bf_rne(fmaxf(a[1] + bv.y, 0.f)) << 16);
        *(unsigned*)&agg2h[(size_t)node * 32 + lane * 2] = o;
    }
}

// ---------- L0 GEMM chain via MFMA bf16 (MT=64, 4 waves) ----------
// GEMM1: relu(agg@W1+b1) -> GEMM2: BN(.@W2+b2), relu -> GEMM3: .@W1_1 -> z1h
// MFMA 16x16x32 bf16 layouts: A[m=l&15][k=(l>>4)*8+j], B[k=(l>>4)*8+j][n=l&15],
// D[row=(l>>4)*4+r][col=l&15]  (m89-verified C/D mapping)
__global__ __launch_bounds__(256) void gemm_L0(
        const unsigned short* __restrict__ aggh, unsigned short* __restrict__ z1h,
        const unsigned short* __restrict__ W1t,  // [128n][128k] bf16
        const unsigned short* __restrict__ W2t,  // [128n][128k] bf16
        const unsigned short* __restrict__ W3t,  // [64n][128k] bf16
        const float* __restrict__ b1, const float* __restrict__ b2,
        const float* __restrict__ gamma, const float* __restrict__ beta,
        const float* __restrict__ mean, const float* __restrict__ var) {
    constexpr int MT = 64, LDA = 136;   // bf16 units; 272B row stride
    __shared__ __align__(16) unsigned short shA[MT * LDA];
    __shared__ __align__(16) unsigned short shB[MT * LDA];
    const int tid = threadIdx.x;
    const int wave = tid >> 6, lane = tid & 63;
    const int nodeBase = blockIdx.x * MT;
    const int lr = lane & 15;
    const int lg = lane >> 4;
    const int lk = lg * 8;
    const int n0 = wave * 32;

    // stage bf16 agg tile -> shA, coalesced 16B
    #pragma unroll
    for (int j = 0; j < 4; j++) {
        int f = tid + j * 256;
        int row = f >> 4, c = f & 15;
        int node = nodeBase + row;
        uint4 v = (node < NN) ? ((const uint4*)aggh)[(size_t)node * 16 + c]
                              : make_uint4(0u, 0u, 0u, 0u);
        *(uint4*)&shA[row * LDA + c * 8] = v;
    }
    __syncthreads();

    f32x4 acc[4][2];

    // GEMM1: h1 = relu(A @ W1 + b1); wave owns cols [n0, n0+32)
    {
        float bv0 = b1[n0 + lr], bv1 = b1[n0 + 16 + lr];
        #pragma unroll
        for (int m = 0; m < 4; m++) {
            f32x4 c0 = {bv0, bv0, bv0, bv0};
            f32x4 c1 = {bv1, bv1, bv1, bv1};
            acc[m][0] = c0; acc[m][1] = c1;
        }
        #pragma unroll
        for (int ks = 0; ks < 4; ks++) {
            const int k0 = ks * 32 + lk;
            bf16x8 wb0 = *(const bf16x8*)&W1t[(n0 + lr) * 128 + k0];
            bf16x8 wb1 = *(const bf16x8*)&W1t[(n0 + 16 + lr) * 128 + k0];
            #pragma unroll
            for (int m = 0; m < 4; m++) {
                bf16x8 af = *(const bf16x8*)&shA[(m * 16 + lr) * LDA + k0];
                acc[m][0] = __builtin_amdgcn_mfma_f32_16x16x32_bf16(af, wb0, acc[m][0], 0, 0, 0);
                acc[m][1] = __builtin_amdgcn_mfma_f32_16x16x32_bf16(af, wb1, acc[m][1], 0, 0, 0);
            }
        }
    }
    #pragma unroll
    for (int m = 0; m < 4; m++) {
        #pragma unroll
        for (int nt = 0; nt < 2; nt++) {
            #pragma unroll
            for (int r = 0; r < 4; r++) {
                shB[(m * 16 + lg * 4 + r) * LDA + (n0 + nt * 16 + lr)] =
                    f2bf_rne(fmaxf(acc[m][nt][r], 0.f));
            }
        }
    }
    __syncthreads();

    // GEMM2: h2 = relu(BN(h1 @ W2 + b2))
    {
        float bv0 = b2[n0 + lr], bv1 = b2[n0 + 16 + lr];
        #pragma unroll
        for (int m = 0; m < 4; m++) {
            f32x4 c0 = {bv0, bv0, bv0, bv0};
            f32x4 c1 = {bv1, bv1, bv1, bv1};
            acc[m][0] = c0; acc[m][1] = c1;
        }
        #pragma unroll
        for (int ks = 0; ks < 4; ks++) {
            const int k0 = ks * 32 + lk;
            bf16x8 wb0 = *(const bf16x8*)&W2t[(n0 + lr) * 128 + k0];
            bf16x8 wb1 = *(const bf16x8*)&W2t[(n0 + 16 + lr) * 128 + k0];
            #pragma unroll
            for (int m = 0; m < 4; m++) {
                bf16x8 af = *(const bf16x8*)&shB[(m * 16 + lr) * LDA + k0];
                acc[m][0] = __builtin_amdgcn_mfma_f32_16x16x32_bf16(af, wb0, acc[m][0], 0, 0, 0);
                acc[m][1] = __builtin_amdgcn_mfma_f32_16x16x32_bf16(af, wb1, acc[m][1], 0, 0, 0);
            }
        }
    }
    float s0 = gamma[n0 + lr]      * (1.0f / sqrtf(var[n0 + lr] + 1e-5f));
    float t0 = beta[n0 + lr]       - mean[n0 + lr] * s0;
    float s1 = gamma[n0 + 16 + lr] * (1.0f / sqrtf(var[n0 + 16 + lr] + 1e-5f));
    float t1 = beta[n0 + 16 + lr]  - mean[n0 + 16 + lr] * s1;
    #pragma unroll
    for (int m = 0; m < 4; m++) {
        #pragma unroll
        for (int nt = 0; nt < 2; nt++) {
            float sc = nt ? s1 : s0, sf = nt ? t1 : t0;
            #pragma unroll
            for (int r = 0; r < 4; r++) {
                float y = fmaxf(fmaf(acc[m][nt][r], sc, sf), 0.f);
                shA[(m * 16 + lg * 4 + r) * LDA + (n0 + nt * 16 + lr)] = f2bf_rne(y);
            }
        }
    }
    __syncthreads();

    // GEMM3: z1 = h2 @ W1_1; wave owns cols [wave*16, +16)
    f32x4 a3[4];
    #pragma unroll
    for (int m = 0; m < 4; m++) {
        f32x4 z = {0.f, 0.f, 0.f, 0.f};
        a3[m] = z;
    }
    #pragma unroll
    for (int ks = 0; ks < 4; ks++) {
        const int k0 = ks * 32 + lk;
        bf16x8 wb = *(const bf16x8*)&W3t[(wave * 16 + lr) * 128 + k0];
        #pragma unroll
        for (int m = 0; m < 4; m++) {
            bf16x8 af = *(const bf16x8*)&shA[(m * 16 + lr) * LDA + k0];
            a3[m] = __builtin_amdgcn_mfma_f32_16x16x32_bf16(af, wb, a3[m], 0, 0, 0);
        }
    }
    #pragma unroll
    for (int m = 0; m < 4; m++) {
        #pragma unroll
        for (int r = 0; r < 4; r++) {
            int node = nodeBase + m * 16 + lg * 4 + r;
            if (node < NN)
                z1h[(size_t)node * 64 + wave * 16 + lr] = f2bf_rne(a3[m][r]);
        }
    }
}

// ---------- L1 GEMM chain via MFMA (MT=64, 4 waves): agg1(64,relu'd) @ W2_1+BN+relu -> @W1_2 -> z2h ----------
__global__ __launch_bounds__(256) void gemm_L1(
        const unsigned short* __restrict__ agg1h, unsigned short* __restrict__ z2h,
        const unsigned short* __restrict__ W21t,  // [64n][64k] bf16
        const unsigned short* __restrict__ W12t,  // [32n][64k] bf16
        const float* __restrict__ b2, const float* __restrict__ gamma,
        const float* __restrict__ beta, const float* __restrict__ mean,
        const float* __restrict__ var) {
    constexpr int MT = 64, LDA = 72;   // bf16; 144B row stride (2-way bank alias, free)
    __shared__ __align__(16) unsigned short shA[MT * LDA];
    __shared__ __align__(16) unsigned short shB[MT * LDA];
    const int tid = threadIdx.x;
    const int wave = tid >> 6, lane = tid & 63;
    const int nodeBase = blockIdx.x * MT;
    const int lr = lane & 15;
    const int lg = lane >> 4;
    const int lk = lg * 8;
    const int n0 = wave * 16;       // GEMM_A output-column base

    // stage agg1 tile (bias+relu already applied by gather_L1)
    #pragma unroll
    for (int j = 0; j < 2; j++) {
        int f = tid + j * 256;              // 512 uint4 (8 per row)
        int row = f >> 3, c = f & 7;
        int node = nodeBase + row;
        uint4 v = (node < NN) ? ((const uint4*)agg1h)[(size_t)node * 8 + c]
                              : make_uint4(0u, 0u, 0u, 0u);
        *(uint4*)&shA[row * LDA + c * 8] = v;
    }
    __syncthreads();

    // GEMM_A: h2 = relu(BN(A @ W2_1 + b2)); wave owns cols [n0, n0+16)
    f32x4 acc[4];
    {
        float bv = b2[n0 + lr];
        #pragma unroll
        for (int m = 0; m < 4; m++) {
            f32x4 c0 = {bv, bv, bv, bv};
            acc[m] = c0;
        }
        #pragma unroll
        for (int ks = 0; ks < 2; ks++) {
            const int k0 = ks * 32 + lk;
            bf16x8 wb = *(const bf16x8*)&W21t[(n0 + lr) * 64 + k0];
            #pragma unroll
            for (int m = 0; m < 4; m++) {
                bf16x8 af = *(const bf16x8*)&shA[(m * 16 + lr) * LDA + k0];
                acc[m] = __builtin_amdgcn_mfma_f32_16x16x32_bf16(af, wb, acc[m], 0, 0, 0);
            }
        }
    }
    float sc = gamma[n0 + lr] * (1.0f / sqrtf(var[n0 + lr] + 1e-5f));
    float sf = beta[n0 + lr] - mean[n0 + lr] * sc;
    #pragma unroll
    for (int m = 0; m < 4; m++) {
        #pragma unroll
        for (int r = 0; r < 4; r++) {
            float y = fmaxf(fmaf(acc[m][r], sc, sf), 0.f);
            shB[(m * 16 + lg * 4 + r) * LDA + (n0 + lr)] = f2bf_rne(y);
        }
    }
    __syncthreads();

    // GEMM_B: z2 = h2 @ W1_2 (64->32). wave: rows [(w>>1)*32,+32), cols [(w&1)*16,+16)
    const int rh = (wave >> 1) * 32, ch = (wave & 1) * 16;
    f32x4 a3[2];
    {
        f32x4 z = {0.f, 0.f, 0.f, 0.f};
        a3[0] = z; a3[1] = z;
    }
    #pragma unroll
    for (int ks = 0; ks < 2; ks++) {
        const int k0 = ks * 32 + lk;
        bf16x8 wb = *(const bf16x8*)&W12t[(ch + lr) * 64 + k0];
        #pragma unroll
        for (int m = 0; m < 2; m++) {
            bf16x8 af = *(const bf16x8*)&shB[(rh + m * 16 + lr) * LDA + k0];
            a3[m] = __builtin_amdgcn_mfma_f32_16x16x32_bf16(af, wb, a3[m], 0, 0, 0);
        }
    }
    #pragma unroll
    for (int m = 0; m < 2; m++) {
        #pragma unroll
        for (int r = 0; r < 4; r++) {
            int node = nodeBase + rh + m * 16 + lg * 4 + r;
            if (node < NN)
                z2h[(size_t)node * 32 + ch + lr] = f2bf_rne(a3[m][r]);
        }
    }
}

// ---------- L2 GEMM (MT=32): agg2(32,relu'd) @ W2_2 + BN -> dot W_lin -> logits ----------
__global__ __launch_bounds__(256) void gemm_L2(
        const unsigned short* __restrict__ agg2h, float* __restrict__ logits,
        const float* __restrict__ W2, const float* __restrict__ b2,
        const float* __restrict__ gamma, const float* __restrict__ beta,
        const float* __restrict__ mean, const float* __restrict__ var,
        const float* __restrict__ Wl, const float* __restrict__ bl) {
    constexpr int MT = 32, LD = 36;
    __shared__ float sh[MT * LD];
    const int tid = threadIdx.x;
    const int nodeBase = blockIdx.x * MT;

    // stage: 32 nodes x 32 bf16; one uint2 (4 bf16) per thread
    {
        int row = tid >> 3, c = tid & 7;
        int node = nodeBase + row;
        uint2 v = (node < NN) ? ((const uint2*)agg2h)[(size_t)node * 8 + c]
                              : make_uint2(0u, 0u);
        sh[row * LD + c * 4 + 0] = BF2F_LO(v.x);
        sh[row * LD + c * 4 + 1] = BF2F_HI(v.x);
        sh[row * LD + c * 4 + 2] = BF2F_LO(v.y);
        sh[row * LD + c * 4 + 3] = BF2F_HI(v.y);
    }
    __syncthreads();

    // GEMM: 32->32 (W2_2) + BN (no relu), dot W_lin. CT=8, RT=32
    const int colid = tid % 8, rowid = tid / 8;
    const int c0 = colid * 4, r0 = rowid;
    float acc[4];
    {
        float4 bv = *(const float4*)&b2[c0];
        acc[0] = bv.x; acc[1] = bv.y; acc[2] = bv.z; acc[3] = bv.w;
        #pragma unroll
        for (int k4 = 0; k4 < 8; k4++) {
            float4 w[4];
            #pragma unroll
            for (int kk = 0; kk < 4; kk++)
                w[kk] = *(const float4*)&W2[(k4 * 4 + kk) * 32 + c0];
            float4 a = *(const float4*)&sh[r0 * LD + k4 * 4];
            const float av[4] = {a.x, a.y, a.z, a.w};
            #pragma unroll
            for (int kk = 0; kk < 4; kk++) {
                const float* wp = (const float*)&w[kk];
                #pragma unroll
                for (int j = 0; j < 4; j++)
                    acc[j] = fmaf(av[kk], wp[j], acc[j]);
            }
        }
    }
    float4 gv = *(const float4*)&gamma[c0];
    float4 bev = *(const float4*)&beta[c0];
    float4 mv = *(const float4*)&mean[c0];
    float4 vv = *(const float4*)&var[c0];
    float4 wl = *(const float4*)&Wl[c0];
    float p = 0.f;
    {
        const float* gp = (const float*)&gv; const float* bp = (const float*)&bev;
        const float* mp = (const float*)&mv; const float* vp = (const float*)&vv;
        const float* wp = (const float*)&wl;
        #pragma unroll
        for (int j = 0; j < 4; j++) {
            float sc = gp[j] * (1.0f / sqrtf(vp[j] + 1e-5f));
            float y = (acc[j] - mp[j]) * sc + bp[j];
            p = fmaf(y, wp[j], p);
        }
    }
    p += __shfl_xor(p, 1);
    p += __shfl_xor(p, 2);
    p += __shfl_xor(p, 4);
    int node = nodeBase + r0;
    if ((tid & 7) == 0 && node < NN)
        logits[node] = (p + bl[0]) * 0.2f;
}

// ---------- head ----------
__global__ __launch_bounds__(256) void seg_softmax(
        const float* __restrict__ logits, const int* __restrict__ gstart,
        float* __restrict__ out) {
    __shared__ float slog[1024];
    __shared__ float sred[4];
    __shared__ float sbc[2];
    int g = blockIdx.x;
    int beg = gstart[g], end = gstart[g + 1];
    int cnt = end - beg;
    int t = threadIdx.x;
    if (cnt <= 0) return;
    bool fits = (cnt <= 1024);

    float lmax = -3.402823466e+38f;
    for (int i = t; i < cnt; i += 256) {
        float lg = logits[beg + i];
        if (fits) slog[i] = lg;
        lmax = fmaxf(lmax, lg);
    }
    #pragma unroll
    for (int off = 32; off > 0; off >>= 1)
        lmax = fmaxf(lmax, __shfl_down(lmax, off));
    if ((t & 63) == 0) sred[t >> 6] = lmax;
    __syncthreads();
    if (t == 0) sbc[0] = fmaxf(fmaxf(sred[0], sred[1]), fmaxf(sred[2], sred[3]));
    __syncthreads();
    float gm = sbc[0];

    float lsum = 0.f;
    for (int i = t; i < cnt; i += 256) {
        float lg = fits ? slog[i] : logits[beg + i];
        float e = expf(lg - gm);
        if (fits) slog[i] = e;
        lsum += e;
    }
    #pragma unroll
    for (int off = 32; off > 0; off >>= 1)
        lsum += __shfl_down(lsum, off);
    __syncthreads();
    if ((t & 63) == 0) sred[t >> 6] = lsum;
    __syncthreads();
    if (t == 0) sbc[1] = (sred[0] + sred[1]) + (sred[2] + sred[3]);
    __syncthreads();
    float inv = 1.0f / sbc[1];

    for (int i = t; i < cnt; i += 256) {
        float e = fits ? slog[i] : expf(logits[beg + i] - gm);
        out[beg + i] = e * inv;
    }
}

// ---------- launch ----------
extern "C" void kernel_launch(void* const* d_in, const int* in_sizes, int n_in,
                              void* d_out, int out_size, void* d_ws, size_t ws_size,
                              hipStream_t stream) {
    const float* x    = (const float*)d_in[0];
    const int*   ei   = (const int*)d_in[1];
    const int*   srcI = ei;
    const int*   dstI = ei + NE;
    const int*   batch = (const int*)d_in[2];

    const float* P[29];
    for (int i = 0; i < 29; i++) P[i] = (const float*)d_in[i];
    const float* Wlin = P[27];
    const float* blin = P[28];

    unsigned short* xh  = (unsigned short*)d_ws;       // N x 128 bf16
    unsigned short* z1h = xh + (size_t)NN * 128;       // N x 64 bf16
    unsigned short* z2h = z1h + (size_t)NN * 64;       // N x 32 bf16
    float* logits = (float*)(z2h + (size_t)NN * 32);   // N
    int* gstart = (int*)(logits + NN);                 // NG+1
    int* deg    = gstart + NG + 1;                     // N
    int* iscan  = deg + NN;                            // N
    int* rowptr = iscan + NN;                          // N+1
    int* bsum   = rowptr + NN + 1;                     // NB
    int* boff   = bsum + NB;                           // NB
    uintptr_t eal = ((uintptr_t)(boff + NB) + 15) & ~(uintptr_t)15;
    int* eoff   = (int*)eal;                           // E (16B aligned)
    int* esrc   = eoff + NE;                           // E
    uintptr_t pal = ((uintptr_t)(esrc + NE) + 255) & ~(uintptr_t)255;
    unsigned short* aggh  = (unsigned short*)pal;      // N x 128 bf16
    unsigned short* W1t   = aggh + (size_t)NN * 128;   // 128x128 bf16 [n][k]
    unsigned short* W2t   = W1t + 16384;               // 128x128 bf16 [n][k]
    unsigned short* W3t   = W2t + 16384;               // 64x128 bf16 [n][k]
    unsigned short* W21t  = W3t + 8192;                // 64x64 bf16 [n][k]
    unsigned short* W12t  = W21t + 4096;               // 32x64 bf16 [n][k]
    unsigned short* agg1h = W12t + 2048;               // N x 64 bf16
    unsigned short* agg2h = agg1h + (size_t)NN * 64;   // N x 32 bf16
    float* outp = (float*)d_out;

    const int TB = 256;

    // merged convert + CSR histogram (6250 blocks; 32 edge-quads spread over 4 waves)
    hipMemsetAsync(deg, 0, NN * sizeof(int), stream);
    conv_hist<<<(N4 + TB - 1) / TB, TB, 0, stream>>>(
        (const float4*)x, (ushort4*)xh, (const int4*)dstI, deg, (int4*)eoff);

    block_scan<<<NB, 256, 0, stream>>>(deg, iscan, bsum,
        P[3], P[5], P[11], P[13], P[19], W1t, W2t, W3t, W21t, W12t);
    scan_bsum<<<1, 256, 0, stream>>>(bsum, boff);
    finalize_bounds<<<NB, 256, 0, stream>>>(deg, iscan, boff, rowptr, batch, gstart);
    fill_csr2<<<(NQ + TB - 1) / TB, TB, 0, stream>>>(
        (const int4*)srcI, (const int4*)dstI, rowptr, (const int4*)eoff, esrc);

    const int GB   = (NN + 3) / 4;     // gathers: 1 wave/node
    const int FB64 = (NN + 63) / 64;
    const int FB32 = (NN + 31) / 32;

    gather_L0<<<GB, 256, 0, stream>>>(xh, esrc, rowptr, aggh);
    gemm_L0<<<FB64, 256, 0, stream>>>(aggh, z1h, W1t, W2t, W3t,
        P[4], P[6], P[7], P[8], P[9], P[10]);
    gather_L1<<<GB, 256, 0, stream>>>(z1h, esrc, rowptr, P[12], agg1h);
    gemm_L1<<<FB64, 256, 0, stream>>>(agg1h, z2h, W21t, W12t,
        P[14], P[15], P[16], P[17], P[18]);
    gather_L2<<<GB, 256, 0, stream>>>(z2h, esrc, rowptr, P[20], agg2h);
    gemm_L2<<<FB32, 256, 0, stream>>>(agg2h, logits,
        P[21], P[22], P[23], P[24], P[25], P[26], Wlin, blin);

    seg_softmax<<<NG, 256, 0, stream>>>(logits, gstart, outp);
}

// Round 9
// 283.376 us; speedup vs baseline: 1.0158x; 1.0158x over previous
//
#include <hip/hip_runtime.h>

#define NN 50000
#define NE 800000
#define NG 256
#define NB ((NN + 255) / 256)   // scan blocks
#define N4 (NN * 128 / 4)       // float4 count of x (1.6M)
#define NQ (NE / 4)             // edge quads (200000)

typedef __attribute__((ext_vector_type(8))) short bf16x8;
typedef __attribute__((ext_vector_type(4))) float f32x4;

// ---------- bf16 helpers ----------
__device__ __forceinline__ unsigned short f2bf_rne(float f) {
    unsigned u = __float_as_uint(f);
    u += 0x7fffu + ((u >> 16) & 1u);   // round-to-nearest-even
    return (unsigned short)(u >> 16);
}
#define BF2F_LO(u) __uint_as_float((u) << 16)
#define BF2F_HI(u) __uint_as_float((u) & 0xffff0000u)

// ---------- merged: x->bf16 convert + XCD-private degree histogram ----------
// deg_priv[xcd][node]: each cache line touched by exactly ONE XCD -> atomics
// stay L2-resident (no cross-XCD line ping-pong through the fabric).
// eoff packs (xcd<<16)|local_offset; per-(node,xcd) slot ranges are disjoint.
__global__ void conv_hist(const float4* __restrict__ x, ushort4* __restrict__ xh,
                          const int4* __restrict__ dst4, int* __restrict__ deg_priv,
                          uint4* __restrict__ eoffx4) {
    int i = blockIdx.x * 256 + threadIdx.x;
    if (i < N4) {
        float4 v = x[i];
        ushort4 o;
        o.x = f2bf_rne(v.x); o.y = f2bf_rne(v.y);
        o.z = f2bf_rne(v.z); o.w = f2bf_rne(v.w);
        xh[i] = o;
    }
    int wv = threadIdx.x >> 6, ln = threadIdx.x & 63;
    if (ln < 8) {
        int q = blockIdx.x * 32 + wv * 8 + ln;   // 6250 blocks * 32 = NQ exactly
        if (q < NQ) {
            unsigned xcd;
            asm volatile("s_getreg_b32 %0, hwreg(HW_REG_XCC_ID)" : "=s"(xcd));
            xcd &= 7u;
            int* mydeg = deg_priv + (size_t)xcd * NN;
            int4 d = dst4[q];
            unsigned o0 = (unsigned)atomicAdd(&mydeg[d.x], 1);
            unsigned o1 = (unsigned)atomicAdd(&mydeg[d.y], 1);
            unsigned o2 = (unsigned)atomicAdd(&mydeg[d.z], 1);
            unsigned o3 = (unsigned)atomicAdd(&mydeg[d.w], 1);
            unsigned tag = xcd << 16;
            eoffx4[q] = make_uint4(tag | o0, tag | o1, tag | o2, tag | o3);
        }
    }
}

// ---------- CSR scan: reduce 8 XCD copies -> deg + per-XCD bases, block scan ----------
// (+ weight transpose/convert side-work)
__global__ void block_scan(const int* __restrict__ deg_priv, int* __restrict__ deg,
                           int* __restrict__ base, int* __restrict__ iscan,
                           int* __restrict__ bsum,
                           const float* __restrict__ W1, const float* __restrict__ W2,
                           const float* __restrict__ W3,
                           const float* __restrict__ W21, const float* __restrict__ W12,
                           unsigned short* __restrict__ W1t,
                           unsigned short* __restrict__ W2t,
                           unsigned short* __restrict__ W3t,
                           unsigned short* __restrict__ W21t,
                           unsigned short* __restrict__ W12t) {
    // weight prep: Wt[n][k] = bf16(W[k][n]) (independent side-work)
    int gidx = blockIdx.x * 256 + threadIdx.x;
    if (gidx < 16384) {
        int n = gidx >> 7, k = gidx & 127;
        W1t[gidx] = f2bf_rne(W1[k * 128 + n]);
        W2t[gidx] = f2bf_rne(W2[k * 128 + n]);
    } else if (gidx < 24576) {
        int i2 = gidx - 16384;
        int n = i2 >> 7, k = i2 & 127;      // n in [0,64), k in [0,128)
        W3t[i2] = f2bf_rne(W3[k * 64 + n]);
    } else if (gidx < 28672) {
        int i3 = gidx - 24576;
        int n = i3 >> 6, k = i3 & 63;       // 64x64
        W21t[i3] = f2bf_rne(W21[k * 64 + n]);
    } else if (gidx < 30720) {
        int i4 = gidx - 28672;
        int n = i4 >> 6, k = i4 & 63;       // n in [0,32), k in [0,64)
        W12t[i4] = f2bf_rne(W12[k * 32 + n]);
    }

    __shared__ int sh[256];
    int t = threadIdx.x;
    int i = blockIdx.x * 256 + t;
    int v = 0;
    if (i < NN) {
        int run = 0;
        #pragma unroll
        for (int xx = 0; xx < 8; xx++) {
            base[(size_t)xx * NN + i] = run;
            run += deg_priv[(size_t)xx * NN + i];
        }
        deg[i] = run;
        v = run;
    }
    sh[t] = v;
    __syncthreads();
    #pragma unroll
    for (int off = 1; off < 256; off <<= 1) {
        int add = (t >= off) ? sh[t - off] : 0;
        __syncthreads();
        sh[t] += add;
        __syncthreads();
    }
    if (i < NN) iscan[i] = sh[t];
    if (t == 255) bsum[blockIdx.x] = sh[255];
}

// merged: bsum prefix (in-block reduce) + rowptr finalize + graph-bounds
__global__ void finalize_bounds(const int* __restrict__ deg, const int* __restrict__ iscan,
                                const int* __restrict__ bsum, int* __restrict__ rowptr,
                                const int* __restrict__ batch, int* __restrict__ gstart) {
    __shared__ int sb[256];
    int t = threadIdx.x;
    sb[t] = (t < blockIdx.x) ? bsum[t] : 0;   // blockIdx.x <= NB-1 = 195 < 256
    __syncthreads();
    #pragma unroll
    for (int off = 128; off > 0; off >>= 1) {
        if (t < off) sb[t] += sb[t + off];
        __syncthreads();
    }
    int boff = sb[0];   // exclusive block offset

    int i = blockIdx.x * 256 + t;
    if (i < NN) {
        rowptr[i] = iscan[i] - deg[i] + boff;
        int b = batch[i];
        if (i == 0) {
            for (int g = 0; g <= b; g++) gstart[g] = 0;
        } else {
            int p = batch[i - 1];
            for (int g = p + 1; g <= b; g++) gstart[g] = i;
        }
        if (i == NN - 1) {
            for (int g = b + 1; g <= NG; g++) gstart[g] = NN;
        }
    }
    if (i == 0) rowptr[NN] = NE;
}

// 4 edges per thread: slot = rowptr[d] + base[xcd][d] + local_off
__global__ void fill_csr2(const int4* __restrict__ src4, const int4* __restrict__ dst4,
                          const int* __restrict__ rowptr, const int* __restrict__ base,
                          const uint4* __restrict__ eoffx4, int* __restrict__ esrc) {
    int q = blockIdx.x * 256 + threadIdx.x;
    if (q >= NQ) return;
    int4 s = src4[q];
    int4 d = dst4[q];
    uint4 e = eoffx4[q];
    int p0 = rowptr[d.x] + base[(size_t)(e.x >> 16) * NN + d.x] + (int)(e.x & 0xffffu);
    int p1 = rowptr[d.y] + base[(size_t)(e.y >> 16) * NN + d.y] + (int)(e.y & 0xffffu);
    int p2 = rowptr[d.z] + base[(size_t)(e.z >> 16) * NN + d.z] + (int)(e.z & 0xffffu);
    int p3 = rowptr[d.w] + base[(size_t)(e.w >> 16) * NN + d.w] + (int)(e.w & 0xffffu);
    esrc[p0] = s.x;
    esrc[p1] = s.y;
    esrc[p2] = s.z;
    esrc[p3] = s.w;
}

// ---------- bf16 wave-cooperative gathers ----------
// C lane-chunks per row, EPI = 64/C edges per pass; 4x/2x/1x unroll keeps
// up to 4 independent loads in flight.

// 16B-lane variant (rows = 256B): x (128 cols)
template <int C4>
__device__ __forceinline__ void gather_bf16(const uint4* __restrict__ x4,
                                            const int* __restrict__ esrc,
                                            int beg, int cnt, int node, int lane,
                                            float* a /* [8] */) {
    constexpr int EPI = 64 / C4;
    const int chunk = lane & (C4 - 1);
    const int esl   = lane / C4;
    #define ACC_U4(u) do { \
        a[0] += BF2F_LO((u).x); a[1] += BF2F_HI((u).x); \
        a[2] += BF2F_LO((u).y); a[3] += BF2F_HI((u).y); \
        a[4] += BF2F_LO((u).z); a[5] += BF2F_HI((u).z); \
        a[6] += BF2F_LO((u).w); a[7] += BF2F_HI((u).w); } while (0)
    if (esl == 0) { uint4 u = x4[(size_t)node * C4 + chunk]; ACC_U4(u); }
    for (int c = 0; c < cnt; c += 64) {
        int take = min(64, cnt - c);
        int myi = (lane < take) ? esrc[beg + c + lane] : 0;
        int i = 0;
        for (; i + 4 * EPI <= take; i += 4 * EPI) {
            int s0 = __shfl(myi, i + esl);
            int s1 = __shfl(myi, i + EPI + esl);
            int s2 = __shfl(myi, i + 2 * EPI + esl);
            int s3 = __shfl(myi, i + 3 * EPI + esl);
            uint4 u0 = x4[(size_t)s0 * C4 + chunk];
            uint4 u1 = x4[(size_t)s1 * C4 + chunk];
            uint4 u2 = x4[(size_t)s2 * C4 + chunk];
            uint4 u3 = x4[(size_t)s3 * C4 + chunk];
            ACC_U4(u0); ACC_U4(u1); ACC_U4(u2); ACC_U4(u3);
        }
        if (i + 2 * EPI <= take) {
            int s0 = __shfl(myi, i + esl);
            int s1 = __shfl(myi, i + EPI + esl);
            uint4 u0 = x4[(size_t)s0 * C4 + chunk];
            uint4 u1 = x4[(size_t)s1 * C4 + chunk];
            ACC_U4(u0); ACC_U4(u1);
            i += 2 * EPI;
        }
        if (i + EPI <= take) {
            int s = __shfl(myi, i + esl);
            uint4 u = x4[(size_t)s * C4 + chunk];
            ACC_U4(u);
            i += EPI;
        }
        int rem = take - i;
        if (rem > 0) {
            int s = __shfl(myi, i + ((esl < rem) ? esl : 0));
            uint4 u = x4[(size_t)s * C4 + chunk];
            if (esl < rem) ACC_U4(u);
        }
    }
    #undef ACC_U4
    for (int off = 32; off >= C4; off >>= 1) {
        #pragma unroll
        for (int q = 0; q < 8; q++)
            a[q] += __shfl_xor(a[q], off);
    }
}

// 8B-lane variant (rows = 128B): z1 (64 cols). C=16, EPI=4.
template <int C>
__device__ __forceinline__ void gather_bf16_u2(const uint2* __restrict__ x2,
                                               const int* __restrict__ esrc,
                                               int beg, int cnt, int node, int lane,
                                               float* a /* [4] */) {
    constexpr int EPI = 64 / C;
    const int chunk = lane & (C - 1);
    const int esl   = lane / C;
    #define ACC_U2(u) do { \
        a[0] += BF2F_LO((u).x); a[1] += BF2F_HI((u).x); \
        a[2] += BF2F_LO((u).y); a[3] += BF2F_HI((u).y); } while (0)
    if (esl == 0) { uint2 u = x2[(size_t)node * C + chunk]; ACC_U2(u); }
    for (int c = 0; c < cnt; c += 64) {
        int take = min(64, cnt - c);
        int myi = (lane < take) ? esrc[beg + c + lane] : 0;
        int i = 0;
        for (; i + 4 * EPI <= take; i += 4 * EPI) {
            int s0 = __shfl(myi, i + esl);
            int s1 = __shfl(myi, i + EPI + esl);
            int s2 = __shfl(myi, i + 2 * EPI + esl);
            int s3 = __shfl(myi, i + 3 * EPI + esl);
            uint2 u0 = x2[(size_t)s0 * C + chunk];
            uint2 u1 = x2[(size_t)s1 * C + chunk];
            uint2 u2 = x2[(size_t)s2 * C + chunk];
            uint2 u3 = x2[(size_t)s3 * C + chunk];
            ACC_U2(u0); ACC_U2(u1); ACC_U2(u2); ACC_U2(u3);
        }
        if (i + 2 * EPI <= take) {
            int s0 = __shfl(myi, i + esl);
            int s1 = __shfl(myi, i + EPI + esl);
            uint2 u0 = x2[(size_t)s0 * C + chunk];
            uint2 u1 = x2[(size_t)s1 * C + chunk];
            ACC_U2(u0); ACC_U2(u1);
            i += 2 * EPI;
        }
        if (i + EPI <= take) {
            int s = __shfl(myi, i + esl);
            uint2 u = x2[(size_t)s * C + chunk];
            ACC_U2(u);
            i += EPI;
        }
        int rem = take - i;
        if (rem > 0) {
            int s = __shfl(myi, i + ((esl < rem) ? esl : 0));
            uint2 u = x2[(size_t)s * C + chunk];
            if (esl < rem) ACC_U2(u);
        }
    }
    #undef ACC_U2
    for (int off = 32; off >= C; off >>= 1) {
        #pragma unroll
        for (int q = 0; q < 4; q++)
            a[q] += __shfl_xor(a[q], off);
    }
}

// 4B-lane variant (rows = 64B): z2 (32 cols). C=16, EPI=4.
template <int C>
__device__ __forceinline__ void gather_bf16_u1(const unsigned* __restrict__ x1,
                                               const int* __restrict__ esrc,
                                               int beg, int cnt, int node, int lane,
                                               float* a /* [2] */) {
    constexpr int EPI = 64 / C;
    const int chunk = lane & (C - 1);
    const int esl   = lane / C;
    #define ACC_U1(u) do { \
        a[0] += BF2F_LO(u); a[1] += BF2F_HI(u); } while (0)
    if (esl == 0) { unsigned u = x1[(size_t)node * C + chunk]; ACC_U1(u); }
    for (int c = 0; c < cnt; c += 64) {
        int take = min(64, cnt - c);
        int myi = (lane < take) ? esrc[beg + c + lane] : 0;
        int i = 0;
        for (; i + 4 * EPI <= take; i += 4 * EPI) {
            int s0 = __shfl(myi, i + esl);
            int s1 = __shfl(myi, i + EPI + esl);
            int s2 = __shfl(myi, i + 2 * EPI + esl);
            int s3 = __shfl(myi, i + 3 * EPI + esl);
            unsigned u0 = x1[(size_t)s0 * C + chunk];
            unsigned u1 = x1[(size_t)s1 * C + chunk];
            unsigned u2 = x1[(size_t)s2 * C + chunk];
            unsigned u3 = x1[(size_t)s3 * C + chunk];
            ACC_U1(u0); ACC_U1(u1); ACC_U1(u2); ACC_U1(u3);
        }
        if (i + 2 * EPI <= take) {
            int s0 = __shfl(myi, i + esl);
            int s1 = __shfl(myi, i + EPI + esl);
            unsigned u0 = x1[(size_t)s0 * C + chunk];
            unsigned u1 = x1[(size_t)s1 * C + chunk];
            ACC_U1(u0); ACC_U1(u1);
            i += 2 * EPI;
        }
        if (i + EPI <= take) {
            int s = __shfl(myi, i + esl);
            unsigned u = x1[(size_t)s * C + chunk];
            ACC_U1(u);
            i += EPI;
        }
        int rem = take - i;
        if (rem > 0) {
            int s = __shfl(myi, i + ((esl < rem) ? esl : 0));
            unsigned u = x1[(size_t)s * C + chunk];
            if (esl < rem) ACC_U1(u);
        }
    }
    #undef ACC_U1
    for (int off = 32; off >= C; off >>= 1) {
        #pragma unroll
        for (int q = 0; q < 2; q++)
            a[q] += __shfl_xor(a[q], off);
    }
}

// ---------- L0 gather: one wave per node -> bf16 agg ----------
__global__ __launch_bounds__(256) void gather_L0(
        const unsigned short* __restrict__ xh, const int* __restrict__ esrc,
        const int* __restrict__ rowptr, unsigned short* __restrict__ aggh /* N x 128 bf16 */) {
    const int wave = threadIdx.x >> 6, lane = threadIdx.x & 63;
    const int node = blockIdx.x * 4 + wave;
    if (node >= NN) return;
    float a[8] = {0, 0, 0, 0, 0, 0, 0, 0};
    int beg = rowptr[node], end = rowptr[node + 1];
    gather_bf16<16>((const uint4*)xh, esrc, beg, end - beg, node, lane, a);
    if (lane < 16) {
        uint4 o;
        o.x = (unsigned)f2bf_rne(a[0]) | ((unsigned)f2bf_rne(a[1]) << 16);
        o.y = (unsigned)f2bf_rne(a[2]) | ((unsigned)f2bf_rne(a[3]) << 16);
        o.z = (unsigned)f2bf_rne(a[4]) | ((unsigned)f2bf_rne(a[5]) << 16);
        o.w = (unsigned)f2bf_rne(a[6]) | ((unsigned)f2bf_rne(a[7]) << 16);
        *(uint4*)&aggh[(size_t)node * 128 + lane * 8] = o;
    }
}

// ---------- L1 gather: one wave per node; +b1, relu -> bf16 agg1 ----------
__global__ __launch_bounds__(256) void gather_L1(
        const unsigned short* __restrict__ z1h, const int* __restrict__ esrc,
        const int* __restrict__ rowptr, const float* __restrict__ b1,
        unsigned short* __restrict__ agg1h /* N x 64 bf16 */) {
    const int wave = threadIdx.x >> 6, lane = threadIdx.x & 63;
    const int node = blockIdx.x * 4 + wave;
    if (node >= NN) return;
    float a[4] = {0, 0, 0, 0};
    int beg = rowptr[node], end = rowptr[node + 1];
    gather_bf16_u2<16>((const uint2*)z1h, esrc, beg, end - beg, node, lane, a);
    if (lane < 16) {
        float4 bv = *(const float4*)&b1[lane * 4];
        uint2 o;
        o.x = (unsigned)f2bf_rne(fmaxf(a[0] + bv.x, 0.f)) |
              ((unsigned)f2bf_rne(fmaxf(a[1] + bv.y, 0.f)) << 16);
        o.y = (unsigned)f2bf_rne(fmaxf(a[2] + bv.z, 0.f)) |
              ((unsigned)f2bf_rne(fmaxf(a[3] + bv.w, 0.f)) << 16);
        *(uint2*)&agg1h[(size_t)node * 64 + lane * 4] = o;
    }
}

// ---------- L2 gather: one wave per node; +b1, relu -> bf16 agg2 ----------
__global__ __launch_bounds__(256) void gather_L2(
        const unsigned short* __restrict__ z2h, const int* __restrict__ esrc,
        const int* __restrict__ rowptr, const float* __restrict__ b1,
        unsigned short* __restrict__ agg2h /* N x 32 bf16 */) {
    const int wave = threadIdx.x >> 6, lane = threadIdx.x & 63;
    const int node = blockIdx.x * 4 + wave;
    if (node >= NN) return;
    float a[2] = {0, 0};
    int beg = rowptr[node], end = rowptr[node + 1];
    gather_bf16_u1<16>((const unsigned*)z2h, esrc, beg, end - beg, node, lane, a);
    if (lane < 16) {
        float2 bv = *(const float2*)&b1[lane * 2];
        unsigned o = (unsigned)f2bf_rne(fmaxf(a[0] + bv.x, 0.f)) |
                     ((unsigned)f2bf_rne(fmaxf(a[1] + bv.y, 0.f)) << 16);
        *(unsigned*)&agg2h[(size_t)node * 32 + lane * 2] = o;
    }
}

// ---------- L0 GEMM chain via MFMA bf16 (MT=64, 4 waves) ----------
// GEMM1: relu(agg@W1+b1) -> GEMM2: BN(.@W2+b2), relu -> GEMM3: .@W1_1 -> z1h
// MFMA 16x16x32 bf16 layouts: A[m=l&15][k=(l>>4)*8+j], B[k=(l>>4)*8+j][n=l&15],
// D[row=(l>>4)*4+r][col=l&15]  (m89-verified C/D mapping)
__global__ __launch_bounds__(256) void gemm_L0(
        const unsigned short* __restrict__ aggh, unsigned short* __restrict__ z1h,
        const unsigned short* __restrict__ W1t,  // [128n][128k] bf16
        const unsigned short* __restrict__ W2t,  // [128n][128k] bf16
        const unsigned short* __restrict__ W3t,  // [64n][128k] bf16
        const float* __restrict__ b1, const float* __restrict__ b2,
        const float* __restrict__ gamma, const float* __restrict__ beta,
        const float* __restrict__ mean, const float* __restrict__ var) {
    constexpr int MT = 64, LDA = 136;   // bf16 units; 272B row stride
    __shared__ __align__(16) unsigned short shA[MT * LDA];
    __shared__ __align__(16) unsigned short shB[MT * LDA];
    const int tid = threadIdx.x;
    const int wave = tid >> 6, lane = tid & 63;
    const int nodeBase = blockIdx.x * MT;
    const int lr = lane & 15;
    const int lg = lane >> 4;
    const int lk = lg * 8;
    const int n0 = wave * 32;

    // stage bf16 agg tile -> shA, coalesced 16B
    #pragma unroll
    for (int j = 0; j < 4; j++) {
        int f = tid + j * 256;
        int row = f >> 4, c = f & 15;
        int node = nodeBase + row;
        uint4 v = (node < NN) ? ((const uint4*)aggh)[(size_t)node * 16 + c]
                              : make_uint4(0u, 0u, 0u, 0u);
        *(uint4*)&shA[row * LDA + c * 8] = v;
    }
    __syncthreads();

    f32x4 acc[4][2];

    // GEMM1: h1 = relu(A @ W1 + b1); wave owns cols [n0, n0+32)
    {
        float bv0 = b1[n0 + lr], bv1 = b1[n0 + 16 + lr];
        #pragma unroll
        for (int m = 0; m < 4; m++) {
            f32x4 c0 = {bv0, bv0, bv0, bv0};
            f32x4 c1 = {bv1, bv1, bv1, bv1};
            acc[m][0] = c0; acc[m][1] = c1;
        }
        #pragma unroll
        for (int ks = 0; ks < 4; ks++) {
            const int k0 = ks * 32 + lk;
            bf16x8 wb0 = *(const bf16x8*)&W1t[(n0 + lr) * 128 + k0];
            bf16x8 wb1 = *(const bf16x8*)&W1t[(n0 + 16 + lr) * 128 + k0];
            #pragma unroll
            for (int m = 0; m < 4; m++) {
                bf16x8 af = *(const bf16x8*)&shA[(m * 16 + lr) * LDA + k0];
                acc[m][0] = __builtin_amdgcn_mfma_f32_16x16x32_bf16(af, wb0, acc[m][0], 0, 0, 0);
                acc[m][1] = __builtin_amdgcn_mfma_f32_16x16x32_bf16(af, wb1, acc[m][1], 0, 0, 0);
            }
        }
    }
    #pragma unroll
    for (int m = 0; m < 4; m++) {
        #pragma unroll
        for (int nt = 0; nt < 2; nt++) {
            #pragma unroll
            for (int r = 0; r < 4; r++) {
                shB[(m * 16 + lg * 4 + r) * LDA + (n0 + nt * 16 + lr)] =
                    f2bf_rne(fmaxf(acc[m][nt][r], 0.f));
            }
        }
    }
    __syncthreads();

    // GEMM2: h2 = relu(BN(h1 @ W2 + b2))
    {
        float bv0 = b2[n0 + lr], bv1 = b2[n0 + 16 + lr];
        #pragma unroll
        for (int m = 0; m < 4; m++) {
            f32x4 c0 = {bv0, bv0, bv0, bv0};
            f32x4 c1 = {bv1, bv1, bv1, bv1};
            acc[m][0] = c0; acc[m][1] = c1;
        }
        #pragma unroll
        for (int ks = 0; ks < 4; ks++) {
            const int k0 = ks * 32 + lk;
            bf16x8 wb0 = *(const bf16x8*)&W2t[(n0 + lr) * 128 + k0];
            bf16x8 wb1 = *(const bf16x8*)&W2t[(n0 + 16 + lr) * 128 + k0];
            #pragma unroll
            for (int m = 0; m < 4; m++) {
                bf16x8 af = *(const bf16x8*)&shB[(m * 16 + lr) * LDA + k0];
                acc[m][0] = __builtin_amdgcn_mfma_f32_16x16x32_bf16(af, wb0, acc[m][0], 0, 0, 0);
                acc[m][1] = __builtin_amdgcn_mfma_f32_16x16x32_bf16(af, wb1, acc[m][1], 0, 0, 0);
            }
        }
    }
    float s0 = gamma[n0 + lr]      * (1.0f / sqrtf(var[n0 + lr] + 1e-5f));
    float t0 = beta[n0 + lr]       - mean[n0 + lr] * s0;
    float s1 = gamma[n0 + 16 + lr] * (1.0f / sqrtf(var[n0 + 16 + lr] + 1e-5f));
    float t1 = beta[n0 + 16 + lr]  - mean[n0 + 16 + lr] * s1;
    #pragma unroll
    for (int m = 0; m < 4; m++) {
        #pragma unroll
        for (int nt = 0; nt < 2; nt++) {
            float sc = nt ? s1 : s0, sf = nt ? t1 : t0;
            #pragma unroll
            for (int r = 0; r < 4; r++) {
                float y = fmaxf(fmaf(acc[m][nt][r], sc, sf), 0.f);
                shA[(m * 16 + lg * 4 + r) * LDA + (n0 + nt * 16 + lr)] = f2bf_rne(y);
            }
        }
    }
    __syncthreads();

    // GEMM3: z1 = h2 @ W1_1; wave owns cols [wave*16, +16)
    f32x4 a3[4];
    #pragma unroll
    for (int m = 0; m < 4; m++) {
        f32x4 z = {0.f, 0.f, 0.f, 0.f};
        a3[m] = z;
    }
    #pragma unroll
    for (int ks = 0; ks < 4; ks++) {
        const int k0 = ks * 32 + lk;
        bf16x8 wb = *(const bf16x8*)&W3t[(wave * 16 + lr) * 128 + k0];
        #pragma unroll
        for (int m = 0; m < 4; m++) {
            bf16x8 af = *(const bf16x8*)&shA[(m * 16 + lr) * LDA + k0];
            a3[m] = __builtin_amdgcn_mfma_f32_16x16x32_bf16(af, wb, a3[m], 0, 0, 0);
        }
    }
    #pragma unroll
    for (int m = 0; m < 4; m++) {
        #pragma unroll
        for (int r = 0; r < 4; r++) {
            int node = nodeBase + m * 16 + lg * 4 + r;
            if (node < NN)
                z1h[(size_t)node * 64 + wave * 16 + lr] = f2bf_rne(a3[m][r]);
        }
    }
}

// ---------- L1 GEMM chain via MFMA (MT=64, 4 waves): agg1(64,relu'd) @ W2_1+BN+relu -> @W1_2 -> z2h ----------
__global__ __launch_bounds__(256) void gemm_L1(
        const unsigned short* __restrict__ agg1h, unsigned short* __restrict__ z2h,
        const unsigned short* __restrict__ W21t,  // [64n][64k] bf16
        const unsigned short* __restrict__ W12t,  // [32n][64k] bf16
        const float* __restrict__ b2, const float* __restrict__ gamma,
        const float* __restrict__ beta, const float* __restrict__ mean,
        const float* __restrict__ var) {
    constexpr int MT = 64, LDA = 72;   // bf16; 144B row stride (2-way bank alias, free)
    __shared__ __align__(16) unsigned short shA[MT * LDA];
    __shared__ __align__(16) unsigned short shB[MT * LDA];
    const int tid = threadIdx.x;
    const int wave = tid >> 6, lane = tid & 63;
    const int nodeBase = blockIdx.x * MT;
    const int lr = lane & 15;
    const int lg = lane >> 4;
    const int lk = lg * 8;
    const int n0 = wave * 16;       // GEMM_A output-column base

    // stage agg1 tile (bias+relu already applied by gather_L1)
    #pragma unroll
    for (int j = 0; j < 2; j++) {
        int f = tid + j * 256;              // 512 uint4 (8 per row)
        int row = f >> 3, c = f & 7;
        int node = nodeBase + row;
        uint4 v = (node < NN) ? ((const uint4*)agg1h)[(size_t)node * 8 + c]
                              : make_uint4(0u, 0u, 0u, 0u);
        *(uint4*)&shA[row * LDA + c * 8] = v;
    }
    __syncthreads();

    // GEMM_A: h2 = relu(BN(A @ W2_1 + b2)); wave owns cols [n0, n0+16)
    f32x4 acc[4];
    {
        float bv = b2[n0 + lr];
        #pragma unroll
        for (int m = 0; m < 4; m++) {
            f32x4 c0 = {bv, bv, bv, bv};
            acc[m] = c0;
        }
        #pragma unroll
        for (int ks = 0; ks < 2; ks++) {
            const int k0 = ks * 32 + lk;
            bf16x8 wb = *(const bf16x8*)&W21t[(n0 + lr) * 64 + k0];
            #pragma unroll
            for (int m = 0; m < 4; m++) {
                bf16x8 af = *(const bf16x8*)&shA[(m * 16 + lr) * LDA + k0];
                acc[m] = __builtin_amdgcn_mfma_f32_16x16x32_bf16(af, wb, acc[m], 0, 0, 0);
            }
        }
    }
    float sc = gamma[n0 + lr] * (1.0f / sqrtf(var[n0 + lr] + 1e-5f));
    float sf = beta[n0 + lr] - mean[n0 + lr] * sc;
    #pragma unroll
    for (int m = 0; m < 4; m++) {
        #pragma unroll
        for (int r = 0; r < 4; r++) {
            float y = fmaxf(fmaf(acc[m][r], sc, sf), 0.f);
            shB[(m * 16 + lg * 4 + r) * LDA + (n0 + lr)] = f2bf_rne(y);
        }
    }
    __syncthreads();

    // GEMM_B: z2 = h2 @ W1_2 (64->32). wave: rows [(w>>1)*32,+32), cols [(w&1)*16,+16)
    const int rh = (wave >> 1) * 32, ch = (wave & 1) * 16;
    f32x4 a3[2];
    {
        f32x4 z = {0.f, 0.f, 0.f, 0.f};
        a3[0] = z; a3[1] = z;
    }
    #pragma unroll
    for (int ks = 0; ks < 2; ks++) {
        const int k0 = ks * 32 + lk;
        bf16x8 wb = *(const bf16x8*)&W12t[(ch + lr) * 64 + k0];
        #pragma unroll
        for (int m = 0; m < 2; m++) {
            bf16x8 af = *(const bf16x8*)&shB[(rh + m * 16 + lr) * LDA + k0];
            a3[m] = __builtin_amdgcn_mfma_f32_16x16x32_bf16(af, wb, a3[m], 0, 0, 0);
        }
    }
    #pragma unroll
    for (int m = 0; m < 2; m++) {
        #pragma unroll
        for (int r = 0; r < 4; r++) {
            int node = nodeBase + rh + m * 16 + lg * 4 + r;
            if (node < NN)
                z2h[(size_t)node * 32 + ch + lr] = f2bf_rne(a3[m][r]);
        }
    }
}

// ---------- L2 GEMM (MT=32): agg2(32,relu'd) @ W2_2 + BN -> dot W_lin -> logits ----------
__global__ __launch_bounds__(256) void gemm_L2(
        const unsigned short* __restrict__ agg2h, float* __restrict__ logits,
        const float* __restrict__ W2, const float* __restrict__ b2,
        const float* __restrict__ gamma, const float* __restrict__ beta,
        const float* __restrict__ mean, const float* __restrict__ var,
        const float* __restrict__ Wl, const float* __restrict__ bl) {
    constexpr int MT = 32, LD = 36;
    __shared__ float sh[MT * LD];
    const int tid = threadIdx.x;
    const int nodeBase = blockIdx.x * MT;

    // stage: 32 nodes x 32 bf16; one uint2 (4 bf16) per thread
    {
        int row = tid >> 3, c = tid & 7;
        int node = nodeBase + row;
        uint2 v = (node < NN) ? ((const uint2*)agg2h)[(size_t)node * 8 + c]
                              : make_uint2(0u, 0u);
        sh[row * LD + c * 4 + 0] = BF2F_LO(v.x);
        sh[row * LD + c * 4 + 1] = BF2F_HI(v.x);
        sh[row * LD + c * 4 + 2] = BF2F_LO(v.y);
        sh[row * LD + c * 4 + 3] = BF2F_HI(v.y);
    }
    __syncthreads();

    // GEMM: 32->32 (W2_2) + BN (no relu), dot W_lin. CT=8, RT=32
    const int colid = tid % 8, rowid = tid / 8;
    const int c0 = colid * 4, r0 = rowid;
    float acc[4];
    {
        float4 bv = *(const float4*)&b2[c0];
        acc[0] = bv.x; acc[1] = bv.y; acc[2] = bv.z; acc[3] = bv.w;
        #pragma unroll
        for (int k4 = 0; k4 < 8; k4++) {
            float4 w[4];
            #pragma unroll
            for (int kk = 0; kk < 4; kk++)
                w[kk] = *(const float4*)&W2[(k4 * 4 + kk) * 32 + c0];
            float4 a = *(const float4*)&sh[r0 * LD + k4 * 4];
            const float av[4] = {a.x, a.y, a.z, a.w};
            #pragma unroll
            for (int kk = 0; kk < 4; kk++) {
                const float* wp = (const float*)&w[kk];
                #pragma unroll
                for (int j = 0; j < 4; j++)
                    acc[j] = fmaf(av[kk], wp[j], acc[j]);
            }
        }
    }
    float4 gv = *(const float4*)&gamma[c0];
    float4 bev = *(const float4*)&beta[c0];
    float4 mv = *(const float4*)&mean[c0];
    float4 vv = *(const float4*)&var[c0];
    float4 wl = *(const float4*)&Wl[c0];
    float p = 0.f;
    {
        const float* gp = (const float*)&gv; const float* bp = (const float*)&bev;
        const float* mp = (const float*)&mv; const float* vp = (const float*)&vv;
        const float* wp = (const float*)&wl;
        #pragma unroll
        for (int j = 0; j < 4; j++) {
            float sc = gp[j] * (1.0f / sqrtf(vp[j] + 1e-5f));
            float y = (acc[j] - mp[j]) * sc + bp[j];
            p = fmaf(y, wp[j], p);
        }
    }
    p += __shfl_xor(p, 1);
    p += __shfl_xor(p, 2);
    p += __shfl_xor(p, 4);
    int node = nodeBase + r0;
    if ((tid & 7) == 0 && node < NN)
        logits[node] = (p + bl[0]) * 0.2f;
}

// ---------- head ----------
__global__ __launch_bounds__(256) void seg_softmax(
        const float* __restrict__ logits, const int* __restrict__ gstart,
        float* __restrict__ out) {
    __shared__ float slog[1024];
    __shared__ float sred[4];
    __shared__ float sbc[2];
    int g = blockIdx.x;
    int beg = gstart[g], end = gstart[g + 1];
    int cnt = end - beg;
    int t = threadIdx.x;
    if (cnt <= 0) return;
    bool fits = (cnt <= 1024);

    float lmax = -3.402823466e+38f;
    for (int i = t; i < cnt; i += 256) {
        float lg = logits[beg + i];
        if (fits) slog[i] = lg;
        lmax = fmaxf(lmax, lg);
    }
    #pragma unroll
    for (int off = 32; off > 0; off >>= 1)
        lmax = fmaxf(lmax, __shfl_down(lmax, off));
    if ((t & 63) == 0) sred[t >> 6] = lmax;
    __syncthreads();
    if (t == 0) sbc[0] = fmaxf(fmaxf(sred[0], sred[1]), fmaxf(sred[2], sred[3]));
    __syncthreads();
    float gm = sbc[0];

    float lsum = 0.f;
    for (int i = t; i < cnt; i += 256) {
        float lg = fits ? slog[i] : logits[beg + i];
        float e = expf(lg - gm);
        if (fits) slog[i] = e;
        lsum += e;
    }
    #pragma unroll
    for (int off = 32; off > 0; off >>= 1)
        lsum += __shfl_down(lsum, off);
    __syncthreads();
    if ((t & 63) == 0) sred[t >> 6] = lsum;
    __syncthreads();
    if (t == 0) sbc[1] = (sred[0] + sred[1]) + (sred[2] + sred[3]);
    __syncthreads();
    float inv = 1.0f / sbc[1];

    for (int i = t; i < cnt; i += 256) {
        float e = fits ? slog[i] : expf(logits[beg + i] - gm);
        out[beg + i] = e * inv;
    }
}

// ---------- launch ----------
extern "C" void kernel_launch(void* const* d_in, const int* in_sizes, int n_in,
                              void* d_out, int out_size, void* d_ws, size_t ws_size,
                              hipStream_t stream) {
    const float* x    = (const float*)d_in[0];
    const int*   ei   = (const int*)d_in[1];
    const int*   srcI = ei;
    const int*   dstI = ei + NE;
    const int*   batch = (const int*)d_in[2];

    const float* P[29];
    for (int i = 0; i < 29; i++) P[i] = (const float*)d_in[i];
    const float* Wlin = P[27];
    const float* blin = P[28];

    unsigned short* xh  = (unsigned short*)d_ws;       // N x 128 bf16
    unsigned short* z1h = xh + (size_t)NN * 128;       // N x 64 bf16
    unsigned short* z2h = z1h + (size_t)NN * 64;       // N x 32 bf16
    float* logits = (float*)(z2h + (size_t)NN * 32);   // N
    int* gstart = (int*)(logits + NN);                 // NG+1
    int* deg      = gstart + NG + 1;                   // N
    int* deg_priv = deg + NN;                          // 8 x N
    int* base     = deg_priv + 8 * NN;                 // 8 x N
    int* iscan    = base + 8 * NN;                     // N
    int* rowptr   = iscan + NN;                        // N+1
    int* bsum     = rowptr + NN + 1;                   // NB
    uintptr_t eal = ((uintptr_t)(bsum + NB) + 15) & ~(uintptr_t)15;
    unsigned* eoffx = (unsigned*)eal;                  // E packed (16B aligned)
    int* esrc   = (int*)(eoffx + NE);                  // E
    uintptr_t pal = ((uintptr_t)(esrc + NE) + 255) & ~(uintptr_t)255;
    unsigned short* aggh  = (unsigned short*)pal;      // N x 128 bf16
    unsigned short* W1t   = aggh + (size_t)NN * 128;   // 128x128 bf16 [n][k]
    unsigned short* W2t   = W1t + 16384;               // 128x128 bf16 [n][k]
    unsigned short* W3t   = W2t + 16384;               // 64x128 bf16 [n][k]
    unsigned short* W21t  = W3t + 8192;                // 64x64 bf16 [n][k]
    unsigned short* W12t  = W21t + 4096;               // 32x64 bf16 [n][k]
    unsigned short* agg1h = W12t + 2048;               // N x 64 bf16
    unsigned short* agg2h = agg1h + (size_t)NN * 64;   // N x 32 bf16
    float* outp = (float*)d_out;

    const int TB = 256;

    // convert + XCD-private histogram (6250 blocks; 32 edge-quads over 4 waves)
    hipMemsetAsync(deg_priv, 0, 8 * NN * sizeof(int), stream);
    conv_hist<<<(N4 + TB - 1) / TB, TB, 0, stream>>>(
        (const float4*)x, (ushort4*)xh, (const int4*)dstI, deg_priv, (uint4*)eoffx);

    block_scan<<<NB, 256, 0, stream>>>(deg_priv, deg, base, iscan, bsum,
        P[3], P[5], P[11], P[13], P[19], W1t, W2t, W3t, W21t, W12t);
    finalize_bounds<<<NB, 256, 0, stream>>>(deg, iscan, bsum, rowptr, batch, gstart);
    fill_csr2<<<(NQ + TB - 1) / TB, TB, 0, stream>>>(
        (const int4*)srcI, (const int4*)dstI, rowptr, base, (const uint4*)eoffx, esrc);

    const int GB   = (NN + 3) / 4;     // gathers: 1 wave/node
    const int FB64 = (NN + 63) / 64;
    const int FB32 = (NN + 31) / 32;

    gather_L0<<<GB, 256, 0, stream>>>(xh, esrc, rowptr, aggh);
    gemm_L0<<<FB64, 256, 0, stream>>>(aggh, z1h, W1t, W2t, W3t,
        P[4], P[6], P[7], P[8], P[9], P[10]);
    gather_L1<<<GB, 256, 0, stream>>>(z1h, esrc, rowptr, P[12], agg1h);
    gemm_L1<<<FB64, 256, 0, stream>>>(agg1h, z2h, W21t, W12t,
        P[14], P[15], P[16], P[17], P[18]);
    gather_L2<<<GB, 256, 0, stream>>>(z2h, esrc, rowptr, P[20], agg2h);
    gemm_L2<<<FB32, 256, 0, stream>>>(agg2h, logits,
        P[21], P[22], P[23], P[24], P[25], P[26], Wlin, blin);

    seg_softmax<<<NG, 256, 0, stream>>>(logits, gstart, outp);
}

// Round 10
// 262.290 us; speedup vs baseline: 1.0975x; 1.0804x over previous
//
#include <hip/hip_runtime.h>

#define NN 50000
#define NE 800000
#define NG 256
#define N4 (NN * 128 / 4)       // float4 count of x (1.6M)
#define NQ (NE / 4)             // edge quads (200000)
#define CB 64                   // count/scatter blocks
#define QPB (NQ / CB)           // 3125 quads per block (exact)
#define NBK 196                 // dst>>8 buckets (50000/256 rounded up)

typedef __attribute__((ext_vector_type(8))) short bf16x8;
typedef __attribute__((ext_vector_type(4))) float f32x4;

// ---------- bf16 helpers ----------
__device__ __forceinline__ unsigned short f2bf_rne(float f) {
    unsigned u = __float_as_uint(f);
    u += 0x7fffu + ((u >> 16) & 1u);   // round-to-nearest-even
    return (unsigned short)(u >> 16);
}
#define BF2F_LO(u) __uint_as_float((u) << 16)
#define BF2F_HI(u) __uint_as_float((u) & 0xffff0000u)

// ---------- pass 1: x->bf16 convert + per-block LDS bucket histogram ----------
// NO global atomics: blocks 0..CB-1 count dst>>8 into LDS, write cnt1[b][k].
__global__ void conv_count(const float4* __restrict__ x, ushort4* __restrict__ xh,
                           const int4* __restrict__ dst4, int* __restrict__ cnt1) {
    __shared__ int hist[NBK];
    int i = blockIdx.x * 256 + threadIdx.x;
    if (i < N4) {
        float4 v = x[i];
        ushort4 o;
        o.x = f2bf_rne(v.x); o.y = f2bf_rne(v.y);
        o.z = f2bf_rne(v.z); o.w = f2bf_rne(v.w);
        xh[i] = o;
    }
    if (blockIdx.x < CB) {
        int t = threadIdx.x;
        if (t < NBK) hist[t] = 0;
        __syncthreads();
        int qb = blockIdx.x * QPB;
        for (int qi = t; qi < QPB; qi += 256) {
            int4 d = dst4[qb + qi];
            atomicAdd(&hist[d.x >> 8], 1);
            atomicAdd(&hist[d.y >> 8], 1);
            atomicAdd(&hist[d.z >> 8], 1);
            atomicAdd(&hist[d.w >> 8], 1);
        }
        __syncthreads();
        if (t < NBK) cnt1[blockIdx.x * NBK + t] = hist[t];
    }
}

// ---------- pass 2: scan cnt1 -> off1 (per-block bucket bases), bstart ----------
__global__ __launch_bounds__(256) void scan_buckets(
        const int* __restrict__ cnt1, int* __restrict__ off1,
        int* __restrict__ bstart, int* __restrict__ rowptr) {
    __shared__ int c[CB * NBK];   // 50176 B
    __shared__ int sh[256];
    int t = threadIdx.x;
    for (int idx = t; idx < CB * NBK; idx += 256) c[idx] = cnt1[idx];
    __syncthreads();
    int tot = 0;
    if (t < NBK) {
        for (int b = 0; b < CB; b++) {       // column scan in LDS (conflict-free)
            int v = c[b * NBK + t];
            c[b * NBK + t] = tot;
            tot += v;
        }
    }
    sh[t] = (t < NBK) ? tot : 0;
    __syncthreads();
    int v = sh[t];
    #pragma unroll
    for (int off = 1; off < 256; off <<= 1) {
        int add = (t >= off) ? sh[t - off] : 0;
        __syncthreads();
        sh[t] += add;
        __syncthreads();
    }
    int excl = sh[t] - v;
    if (t < NBK) {
        bstart[t] = excl;
        for (int b = 0; b < CB; b++) c[b * NBK + t] += excl;
    }
    if (t == 0) { bstart[NBK] = NE; rowptr[NN] = NE; }
    __syncthreads();
    for (int idx = t; idx < CB * NBK; idx += 256) off1[idx] = c[idx];
}

// ---------- pass 3: scatter edges to bucket-major tmp (LDS cursors) ----------
__global__ __launch_bounds__(256) void scatter1(
        const int4* __restrict__ src4, const int4* __restrict__ dst4,
        const int* __restrict__ off1, int2* __restrict__ tmp) {
    __shared__ int curs[NBK];
    int t = threadIdx.x;
    if (t < NBK) curs[t] = off1[blockIdx.x * NBK + t];
    __syncthreads();
    int qb = blockIdx.x * QPB;
    for (int qi = t; qi < QPB; qi += 256) {
        int4 s = src4[qb + qi];
        int4 d = dst4[qb + qi];
        int p0 = atomicAdd(&curs[d.x >> 8], 1);
        int p1 = atomicAdd(&curs[d.y >> 8], 1);
        int p2 = atomicAdd(&curs[d.z >> 8], 1);
        int p3 = atomicAdd(&curs[d.w >> 8], 1);
        tmp[p0] = make_int2(s.x, d.x);
        tmp[p1] = make_int2(s.y, d.y);
        tmp[p2] = make_int2(s.z, d.z);
        tmp[p3] = make_int2(s.w, d.w);
    }
}

// ---------- pass 4: per-bucket CSR finalize: rowptr + gstart + esrc ----------
// (+ weight transpose/convert side-work: 196 blocks x 256 >= 30720 threads)
__global__ __launch_bounds__(256) void bucket_build(
        const int2* __restrict__ tmp, const int* __restrict__ bstart,
        const int* __restrict__ batch, int* __restrict__ rowptr,
        int* __restrict__ gstart, int* __restrict__ esrc,
        const float* __restrict__ W1, const float* __restrict__ W2,
        const float* __restrict__ W3,
        const float* __restrict__ W21, const float* __restrict__ W12,
        unsigned short* __restrict__ W1t, unsigned short* __restrict__ W2t,
        unsigned short* __restrict__ W3t, unsigned short* __restrict__ W21t,
        unsigned short* __restrict__ W12t) {
    int gidx = blockIdx.x * 256 + threadIdx.x;
    if (gidx < 16384) {
        int n = gidx >> 7, k = gidx & 127;
        W1t[gidx] = f2bf_rne(W1[k * 128 + n]);
        W2t[gidx] = f2bf_rne(W2[k * 128 + n]);
    } else if (gidx < 24576) {
        int i2 = gidx - 16384;
        int n = i2 >> 7, k = i2 & 127;
        W3t[i2] = f2bf_rne(W3[k * 64 + n]);
    } else if (gidx < 28672) {
        int i3 = gidx - 24576;
        int n = i3 >> 6, k = i3 & 63;
        W21t[i3] = f2bf_rne(W21[k * 64 + n]);
    } else if (gidx < 30720) {
        int i4 = gidx - 28672;
        int n = i4 >> 6, k = i4 & 63;
        W12t[i4] = f2bf_rne(W12[k * 32 + n]);
    }

    __shared__ int hist[256];
    __shared__ int sh[256];
    __shared__ int curs[256];
    int t = threadIdx.x, k1 = blockIdx.x;
    int b0 = bstart[k1], b1v = bstart[k1 + 1];
    int cnt = b1v - b0;
    hist[t] = 0;
    __syncthreads();
    for (int e = t; e < cnt; e += 256) {
        int2 sd = tmp[b0 + e];
        atomicAdd(&hist[sd.y & 255], 1);
    }
    __syncthreads();
    int v = hist[t];
    sh[t] = v;
    __syncthreads();
    #pragma unroll
    for (int off = 1; off < 256; off <<= 1) {
        int add = (t >= off) ? sh[t - off] : 0;
        __syncthreads();
        sh[t] += add;
        __syncthreads();
    }
    int excl = sh[t] - v;
    int node = k1 * 256 + t;
    if (node < NN) {
        rowptr[node] = b0 + excl;
        int b = batch[node];
        if (node == 0) {
            for (int g = 0; g <= b; g++) gstart[g] = 0;
        } else {
            int p = batch[node - 1];
            for (int g = p + 1; g <= b; g++) gstart[g] = node;
        }
        if (node == NN - 1) {
            for (int g = b + 1; g <= NG; g++) gstart[g] = NN;
        }
    }
    curs[t] = b0 + excl;
    __syncthreads();
    for (int e = t; e < cnt; e += 256) {
        int2 sd = tmp[b0 + e];
        int slot = atomicAdd(&curs[sd.y & 255], 1);
        esrc[slot] = sd.x;
    }
}

// ---------- bf16 wave-cooperative gathers ----------
// C lane-chunks per row, EPI = 64/C edges per pass; 4x/2x/1x unroll keeps
// up to 4 independent loads in flight.

// 16B-lane variant (rows = 256B): x (128 cols)
template <int C4>
__device__ __forceinline__ void gather_bf16(const uint4* __restrict__ x4,
                                            const int* __restrict__ esrc,
                                            int beg, int cnt, int node, int lane,
                                            float* a /* [8] */) {
    constexpr int EPI = 64 / C4;
    const int chunk = lane & (C4 - 1);
    const int esl   = lane / C4;
    #define ACC_U4(u) do { \
        a[0] += BF2F_LO((u).x); a[1] += BF2F_HI((u).x); \
        a[2] += BF2F_LO((u).y); a[3] += BF2F_HI((u).y); \
        a[4] += BF2F_LO((u).z); a[5] += BF2F_HI((u).z); \
        a[6] += BF2F_LO((u).w); a[7] += BF2F_HI((u).w); } while (0)
    if (esl == 0) { uint4 u = x4[(size_t)node * C4 + chunk]; ACC_U4(u); }
    for (int c = 0; c < cnt; c += 64) {
        int take = min(64, cnt - c);
        int myi = (lane < take) ? esrc[beg + c + lane] : 0;
        int i = 0;
        for (; i + 4 * EPI <= take; i += 4 * EPI) {
            int s0 = __shfl(myi, i + esl);
            int s1 = __shfl(myi, i + EPI + esl);
            int s2 = __shfl(myi, i + 2 * EPI + esl);
            int s3 = __shfl(myi, i + 3 * EPI + esl);
            uint4 u0 = x4[(size_t)s0 * C4 + chunk];
            uint4 u1 = x4[(size_t)s1 * C4 + chunk];
            uint4 u2 = x4[(size_t)s2 * C4 + chunk];
            uint4 u3 = x4[(size_t)s3 * C4 + chunk];
            ACC_U4(u0); ACC_U4(u1); ACC_U4(u2); ACC_U4(u3);
        }
        if (i + 2 * EPI <= take) {
            int s0 = __shfl(myi, i + esl);
            int s1 = __shfl(myi, i + EPI + esl);
            uint4 u0 = x4[(size_t)s0 * C4 + chunk];
            uint4 u1 = x4[(size_t)s1 * C4 + chunk];
            ACC_U4(u0); ACC_U4(u1);
            i += 2 * EPI;
        }
        if (i + EPI <= take) {
            int s = __shfl(myi, i + esl);
            uint4 u = x4[(size_t)s * C4 + chunk];
            ACC_U4(u);
            i += EPI;
        }
        int rem = take - i;
        if (rem > 0) {
            int s = __shfl(myi, i + ((esl < rem) ? esl : 0));
            uint4 u = x4[(size_t)s * C4 + chunk];
            if (esl < rem) ACC_U4(u);
        }
    }
    #undef ACC_U4
    for (int off = 32; off >= C4; off >>= 1) {
        #pragma unroll
        for (int q = 0; q < 8; q++)
            a[q] += __shfl_xor(a[q], off);
    }
}

// 8B-lane variant (rows = 128B): z1 (64 cols). C=16, EPI=4.
template <int C>
__device__ __forceinline__ void gather_bf16_u2(const uint2* __restrict__ x2,
                                               const int* __restrict__ esrc,
                                               int beg, int cnt, int node, int lane,
                                               float* a /* [4] */) {
    constexpr int EPI = 64 / C;
    const int chunk = lane & (C - 1);
    const int esl   = lane / C;
    #define ACC_U2(u) do { \
        a[0] += BF2F_LO((u).x); a[1] += BF2F_HI((u).x); \
        a[2] += BF2F_LO((u).y); a[3] += BF2F_HI((u).y); } while (0)
    if (esl == 0) { uint2 u = x2[(size_t)node * C + chunk]; ACC_U2(u); }
    for (int c = 0; c < cnt; c += 64) {
        int take = min(64, cnt - c);
        int myi = (lane < take) ? esrc[beg + c + lane] : 0;
        int i = 0;
        for (; i + 4 * EPI <= take; i += 4 * EPI) {
            int s0 = __shfl(myi, i + esl);
            int s1 = __shfl(myi, i + EPI + esl);
            int s2 = __shfl(myi, i + 2 * EPI + esl);
            int s3 = __shfl(myi, i + 3 * EPI + esl);
            uint2 u0 = x2[(size_t)s0 * C + chunk];
            uint2 u1 = x2[(size_t)s1 * C + chunk];
            uint2 u2 = x2[(size_t)s2 * C + chunk];
            uint2 u3 = x2[(size_t)s3 * C + chunk];
            ACC_U2(u0); ACC_U2(u1); ACC_U2(u2); ACC_U2(u3);
        }
        if (i + 2 * EPI <= take) {
            int s0 = __shfl(myi, i + esl);
            int s1 = __shfl(myi, i + EPI + esl);
            uint2 u0 = x2[(size_t)s0 * C + chunk];
            uint2 u1 = x2[(size_t)s1 * C + chunk];
            ACC_U2(u0); ACC_U2(u1);
            i += 2 * EPI;
        }
        if (i + EPI <= take) {
            int s = __shfl(myi, i + esl);
            uint2 u = x2[(size_t)s * C + chunk];
            ACC_U2(u);
            i += EPI;
        }
        int rem = take - i;
        if (rem > 0) {
            int s = __shfl(myi, i + ((esl < rem) ? esl : 0));
            uint2 u = x2[(size_t)s * C + chunk];
            if (esl < rem) ACC_U2(u);
        }
    }
    #undef ACC_U2
    for (int off = 32; off >= C; off >>= 1) {
        #pragma unroll
        for (int q = 0; q < 4; q++)
            a[q] += __shfl_xor(a[q], off);
    }
}

// 4B-lane variant (rows = 64B): z2 (32 cols). C=16, EPI=4.
template <int C>
__device__ __forceinline__ void gather_bf16_u1(const unsigned* __restrict__ x1,
                                               const int* __restrict__ esrc,
                                               int beg, int cnt, int node, int lane,
                                               float* a /* [2] */) {
    constexpr int EPI = 64 / C;
    const int chunk = lane & (C - 1);
    const int esl   = lane / C;
    #define ACC_U1(u) do { \
        a[0] += BF2F_LO(u); a[1] += BF2F_HI(u); } while (0)
    if (esl == 0) { unsigned u = x1[(size_t)node * C + chunk]; ACC_U1(u); }
    for (int c = 0; c < cnt; c += 64) {
        int take = min(64, cnt - c);
        int myi = (lane < take) ? esrc[beg + c + lane] : 0;
        int i = 0;
        for (; i + 4 * EPI <= take; i += 4 * EPI) {
            int s0 = __shfl(myi, i + esl);
            int s1 = __shfl(myi, i + EPI + esl);
            int s2 = __shfl(myi, i + 2 * EPI + esl);
            int s3 = __shfl(myi, i + 3 * EPI + esl);
            unsigned u0 = x1[(size_t)s0 * C + chunk];
            unsigned u1 = x1[(size_t)s1 * C + chunk];
            unsigned u2 = x1[(size_t)s2 * C + chunk];
            unsigned u3 = x1[(size_t)s3 * C + chunk];
            ACC_U1(u0); ACC_U1(u1); ACC_U1(u2); ACC_U1(u3);
        }
        if (i + 2 * EPI <= take) {
            int s0 = __shfl(myi, i + esl);
            int s1 = __shfl(myi, i + EPI + esl);
            unsigned u0 = x1[(size_t)s0 * C + chunk];
            unsigned u1 = x1[(size_t)s1 * C + chunk];
            ACC_U1(u0); ACC_U1(u1);
            i += 2 * EPI;
        }
        if (i + EPI <= take) {
            int s = __shfl(myi, i + esl);
            unsigned u = x1[(size_t)s * C + chunk];
            ACC_U1(u);
            i += EPI;
        }
        int rem = take - i;
        if (rem > 0) {
            int s = __shfl(myi, i + ((esl < rem) ? esl : 0));
            unsigned u = x1[(size_t)s * C + chunk];
            if (esl < rem) ACC_U1(u);
        }
    }
    #undef ACC_U1
    for (int off = 32; off >= C; off >>= 1) {
        #pragma unroll
        for (int q = 0; q < 2; q++)
            a[q] += __shfl_xor(a[q], off);
    }
}

// ---------- L0 gather: one wave per node -> bf16 agg ----------
__global__ __launch_bounds__(256) void gather_L0(
        const unsigned short* __restrict__ xh, const int* __restrict__ esrc,
        const int* __restrict__ rowptr, unsigned short* __restrict__ aggh /* N x 128 bf16 */) {
    const int wave = threadIdx.x >> 6, lane = threadIdx.x & 63;
    const int node = blockIdx.x * 4 + wave;
    if (node >= NN) return;
    float a[8] = {0, 0, 0, 0, 0, 0, 0, 0};
    int beg = rowptr[node], end = rowptr[node + 1];
    gather_bf16<16>((const uint4*)xh, esrc, beg, end - beg, node, lane, a);
    if (lane < 16) {
        uint4 o;
        o.x = (unsigned)f2bf_rne(a[0]) | ((unsigned)f2bf_rne(a[1]) << 16);
        o.y = (unsigned)f2bf_rne(a[2]) | ((unsigned)f2bf_rne(a[3]) << 16);
        o.z = (unsigned)f2bf_rne(a[4]) | ((unsigned)f2bf_rne(a[5]) << 16);
        o.w = (unsigned)f2bf_rne(a[6]) | ((unsigned)f2bf_rne(a[7]) << 16);
        *(uint4*)&aggh[(size_t)node * 128 + lane * 8] = o;
    }
}

// ---------- L1 gather: one wave per node; +b1, relu -> bf16 agg1 ----------
__global__ __launch_bounds__(256) void gather_L1(
        const unsigned short* __restrict__ z1h, const int* __restrict__ esrc,
        const int* __restrict__ rowptr, const float* __restrict__ b1,
        unsigned short* __restrict__ agg1h /* N x 64 bf16 */) {
    const int wave = threadIdx.x >> 6, lane = threadIdx.x & 63;
    const int node = blockIdx.x * 4 + wave;
    if (node >= NN) return;
    float a[4] = {0, 0, 0, 0};
    int beg = rowptr[node], end = rowptr[node + 1];
    gather_bf16_u2<16>((const uint2*)z1h, esrc, beg, end - beg, node, lane, a);
    if (lane < 16) {
        float4 bv = *(const float4*)&b1[lane * 4];
        uint2 o;
        o.x = (unsigned)f2bf_rne(fmaxf(a[0] + bv.x, 0.f)) |
              ((unsigned)f2bf_rne(fmaxf(a[1] + bv.y, 0.f)) << 16);
        o.y = (unsigned)f2bf_rne(fmaxf(a[2] + bv.z, 0.f)) |
              ((unsigned)f2bf_rne(fmaxf(a[3] + bv.w, 0.f)) << 16);
        *(uint2*)&agg1h[(size_t)node * 64 + lane * 4] = o;
    }
}

// ---------- L2 gather: one wave per node; +b1, relu -> bf16 agg2 ----------
__global__ __launch_bounds__(256) void gather_L2(
        const unsigned short* __restrict__ z2h, const int* __restrict__ esrc,
        const int* __restrict__ rowptr, const float* __restrict__ b1,
        unsigned short* __restrict__ agg2h /* N x 32 bf16 */) {
    const int wave = threadIdx.x >> 6, lane = threadIdx.x & 63;
    const int node = blockIdx.x * 4 + wave;
    if (node >= NN) return;
    float a[2] = {0, 0};
    int beg = rowptr[node], end = rowptr[node + 1];
    gather_bf16_u1<16>((const unsigned*)z2h, esrc, beg, end - beg, node, lane, a);
    if (lane < 16) {
        float2 bv = *(const float2*)&b1[lane * 2];
        unsigned o = (unsigned)f2bf_rne(fmaxf(a[0] + bv.x, 0.f)) |
                     ((unsigned)f2bf_rne(fmaxf(a[1] + bv.y, 0.f)) << 16);
        *(unsigned*)&agg2h[(size_t)node * 32 + lane * 2] = o;
    }
}

// ---------- L0 GEMM chain via MFMA bf16 (MT=64, 4 waves) ----------
// GEMM1: relu(agg@W1+b1) -> GEMM2: BN(.@W2+b2), relu -> GEMM3: .@W1_1 -> z1h
// MFMA 16x16x32 bf16 layouts: A[m=l&15][k=(l>>4)*8+j], B[k=(l>>4)*8+j][n=l&15],
// D[row=(l>>4)*4+r][col=l&15]  (m89-verified C/D mapping)
__global__ __launch_bounds__(256) void gemm_L0(
        const unsigned short* __restrict__ aggh, unsigned short* __restrict__ z1h,
        const unsigned short* __restrict__ W1t,  // [128n][128k] bf16
        const unsigned short* __restrict__ W2t,  // [128n][128k] bf16
        const unsigned short* __restrict__ W3t,  // [64n][128k] bf16
        const float* __restrict__ b1, const float* __restrict__ b2,
        const float* __restrict__ gamma, const float* __restrict__ beta,
        const float* __restrict__ mean, const float* __restrict__ var) {
    constexpr int MT = 64, LDA = 136;   // bf16 units; 272B row stride
    __shared__ __align__(16) unsigned short shA[MT * LDA];
    __shared__ __align__(16) unsigned short shB[MT * LDA];
    const int tid = threadIdx.x;
    const int wave = tid >> 6, lane = tid & 63;
    const int nodeBase = blockIdx.x * MT;
    const int lr = lane & 15;
    const int lg = lane >> 4;
    const int lk = lg * 8;
    const int n0 = wave * 32;

    // stage bf16 agg tile -> shA, coalesced 16B
    #pragma unroll
    for (int j = 0; j < 4; j++) {
        int f = tid + j * 256;
        int row = f >> 4, c = f & 15;
        int node = nodeBase + row;
        uint4 v = (node < NN) ? ((const uint4*)aggh)[(size_t)node * 16 + c]
                              : make_uint4(0u, 0u, 0u, 0u);
        *(uint4*)&shA[row * LDA + c * 8] = v;
    }
    __syncthreads();

    f32x4 acc[4][2];

    // GEMM1: h1 = relu(A @ W1 + b1); wave owns cols [n0, n0+32)
    {
        float bv0 = b1[n0 + lr], bv1 = b1[n0 + 16 + lr];
        #pragma unroll
        for (int m = 0; m < 4; m++) {
            f32x4 c0 = {bv0, bv0, bv0, bv0};
            f32x4 c1 = {bv1, bv1, bv1, bv1};
            acc[m][0] = c0; acc[m][1] = c1;
        }
        #pragma unroll
        for (int ks = 0; ks < 4; ks++) {
            const int k0 = ks * 32 + lk;
            bf16x8 wb0 = *(const bf16x8*)&W1t[(n0 + lr) * 128 + k0];
            bf16x8 wb1 = *(const bf16x8*)&W1t[(n0 + 16 + lr) * 128 + k0];
            #pragma unroll
            for (int m = 0; m < 4; m++) {
                bf16x8 af = *(const bf16x8*)&shA[(m * 16 + lr) * LDA + k0];
                acc[m][0] = __builtin_amdgcn_mfma_f32_16x16x32_bf16(af, wb0, acc[m][0], 0, 0, 0);
                acc[m][1] = __builtin_amdgcn_mfma_f32_16x16x32_bf16(af, wb1, acc[m][1], 0, 0, 0);
            }
        }
    }
    #pragma unroll
    for (int m = 0; m < 4; m++) {
        #pragma unroll
        for (int nt = 0; nt < 2; nt++) {
            #pragma unroll
            for (int r = 0; r < 4; r++) {
                shB[(m * 16 + lg * 4 + r) * LDA + (n0 + nt * 16 + lr)] =
                    f2bf_rne(fmaxf(acc[m][nt][r], 0.f));
            }
        }
    }
    __syncthreads();

    // GEMM2: h2 = relu(BN(h1 @ W2 + b2))
    {
        float bv0 = b2[n0 + lr], bv1 = b2[n0 + 16 + lr];
        #pragma unroll
        for (int m = 0; m < 4; m++) {
            f32x4 c0 = {bv0, bv0, bv0, bv0};
            f32x4 c1 = {bv1, bv1, bv1, bv1};
            acc[m][0] = c0; acc[m][1] = c1;
        }
        #pragma unroll
        for (int ks = 0; ks < 4; ks++) {
            const int k0 = ks * 32 + lk;
            bf16x8 wb0 = *(const bf16x8*)&W2t[(n0 + lr) * 128 + k0];
            bf16x8 wb1 = *(const bf16x8*)&W2t[(n0 + 16 + lr) * 128 + k0];
            #pragma unroll
            for (int m = 0; m < 4; m++) {
                bf16x8 af = *(const bf16x8*)&shB[(m * 16 + lr) * LDA + k0];
                acc[m][0] = __builtin_amdgcn_mfma_f32_16x16x32_bf16(af, wb0, acc[m][0], 0, 0, 0);
                acc[m][1] = __builtin_amdgcn_mfma_f32_16x16x32_bf16(af, wb1, acc[m][1], 0, 0, 0);
            }
        }
    }
    float s0 = gamma[n0 + lr]      * (1.0f / sqrtf(var[n0 + lr] + 1e-5f));
    float t0 = beta[n0 + lr]       - mean[n0 + lr] * s0;
    float s1 = gamma[n0 + 16 + lr] * (1.0f / sqrtf(var[n0 + 16 + lr] + 1e-5f));
    float t1 = beta[n0 + 16 + lr]  - mean[n0 + 16 + lr] * s1;
    #pragma unroll
    for (int m = 0; m < 4; m++) {
        #pragma unroll
        for (int nt = 0; nt < 2; nt++) {
            float sc = nt ? s1 : s0, sf = nt ? t1 : t0;
            #pragma unroll
            for (int r = 0; r < 4; r++) {
                float y = fmaxf(fmaf(acc[m][nt][r], sc, sf), 0.f);
                shA[(m * 16 + lg * 4 + r) * LDA + (n0 + nt * 16 + lr)] = f2bf_rne(y);
            }
        }
    }
    __syncthreads();

    // GEMM3: z1 = h2 @ W1_1; wave owns cols [wave*16, +16)
    f32x4 a3[4];
    #pragma unroll
    for (int m = 0; m < 4; m++) {
        f32x4 z = {0.f, 0.f, 0.f, 0.f};
        a3[m] = z;
    }
    #pragma unroll
    for (int ks = 0; ks < 4; ks++) {
        const int k0 = ks * 32 + lk;
        bf16x8 wb = *(const bf16x8*)&W3t[(wave * 16 + lr) * 128 + k0];
        #pragma unroll
        for (int m = 0; m < 4; m++) {
            bf16x8 af = *(const bf16x8*)&shA[(m * 16 + lr) * LDA + k0];
            a3[m] = __builtin_amdgcn_mfma_f32_16x16x32_bf16(af, wb, a3[m], 0, 0, 0);
        }
    }
    #pragma unroll
    for (int m = 0; m < 4; m++) {
        #pragma unroll
        for (int r = 0; r < 4; r++) {
            int node = nodeBase + m * 16 + lg * 4 + r;
            if (node < NN)
                z1h[(size_t)node * 64 + wave * 16 + lr] = f2bf_rne(a3[m][r]);
        }
    }
}

// ---------- L1 GEMM chain via MFMA (MT=64, 4 waves): agg1(64,relu'd) @ W2_1+BN+relu -> @W1_2 -> z2h ----------
__global__ __launch_bounds__(256) void gemm_L1(
        const unsigned short* __restrict__ agg1h, unsigned short* __restrict__ z2h,
        const unsigned short* __restrict__ W21t,  // [64n][64k] bf16
        const unsigned short* __restrict__ W12t,  // [32n][64k] bf16
        const float* __restrict__ b2, const float* __restrict__ gamma,
        const float* __restrict__ beta, const float* __restrict__ mean,
        const float* __restrict__ var) {
    constexpr int MT = 64, LDA = 72;   // bf16; 144B row stride (2-way bank alias, free)
    __shared__ __align__(16) unsigned short shA[MT * LDA];
    __shared__ __align__(16) unsigned short shB[MT * LDA];
    const int tid = threadIdx.x;
    const int wave = tid >> 6, lane = tid & 63;
    const int nodeBase = blockIdx.x * MT;
    const int lr = lane & 15;
    const int lg = lane >> 4;
    const int lk = lg * 8;
    const int n0 = wave * 16;       // GEMM_A output-column base

    // stage agg1 tile (bias+relu already applied by gather_L1)
    #pragma unroll
    for (int j = 0; j < 2; j++) {
        int f = tid + j * 256;              // 512 uint4 (8 per row)
        int row = f >> 3, c = f & 7;
        int node = nodeBase + row;
        uint4 v = (node < NN) ? ((const uint4*)agg1h)[(size_t)node * 8 + c]
                              : make_uint4(0u, 0u, 0u, 0u);
        *(uint4*)&shA[row * LDA + c * 8] = v;
    }
    __syncthreads();

    // GEMM_A: h2 = relu(BN(A @ W2_1 + b2)); wave owns cols [n0, n0+16)
    f32x4 acc[4];
    {
        float bv = b2[n0 + lr];
        #pragma unroll
        for (int m = 0; m < 4; m++) {
            f32x4 c0 = {bv, bv, bv, bv};
            acc[m] = c0;
        }
        #pragma unroll
        for (int ks = 0; ks < 2; ks++) {
            const int k0 = ks * 32 + lk;
            bf16x8 wb = *(const bf16x8*)&W21t[(n0 + lr) * 64 + k0];
            #pragma unroll
            for (int m = 0; m < 4; m++) {
                bf16x8 af = *(const bf16x8*)&shA[(m * 16 + lr) * LDA + k0];
                acc[m] = __builtin_amdgcn_mfma_f32_16x16x32_bf16(af, wb, acc[m], 0, 0, 0);
            }
        }
    }
    float sc = gamma[n0 + lr] * (1.0f / sqrtf(var[n0 + lr] + 1e-5f));
    float sf = beta[n0 + lr] - mean[n0 + lr] * sc;
    #pragma unroll
    for (int m = 0; m < 4; m++) {
        #pragma unroll
        for (int r = 0; r < 4; r++) {
            float y = fmaxf(fmaf(acc[m][r], sc, sf), 0.f);
            shB[(m * 16 + lg * 4 + r) * LDA + (n0 + lr)] = f2bf_rne(y);
        }
    }
    __syncthreads();

    // GEMM_B: z2 = h2 @ W1_2 (64->32). wave: rows [(w>>1)*32,+32), cols [(w&1)*16,+16)
    const int rh = (wave >> 1) * 32, ch = (wave & 1) * 16;
    f32x4 a3[2];
    {
        f32x4 z = {0.f, 0.f, 0.f, 0.f};
        a3[0] = z; a3[1] = z;
    }
    #pragma unroll
    for (int ks = 0; ks < 2; ks++) {
        const int k0 = ks * 32 + lk;
        bf16x8 wb = *(const bf16x8*)&W12t[(ch + lr) * 64 + k0];
        #pragma unroll
        for (int m = 0; m < 2; m++) {
            bf16x8 af = *(const bf16x8*)&shB[(rh + m * 16 + lr) * LDA + k0];
            a3[m] = __builtin_amdgcn_mfma_f32_16x16x32_bf16(af, wb, a3[m], 0, 0, 0);
        }
    }
    #pragma unroll
    for (int m = 0; m < 2; m++) {
        #pragma unroll
        for (int r = 0; r < 4; r++) {
            int node = nodeBase + rh + m * 16 + lg * 4 + r;
            if (node < NN)
                z2h[(size_t)node * 32 + ch + lr] = f2bf_rne(a3[m][r]);
        }
    }
}

// ---------- L2 GEMM (MT=32): agg2(32,relu'd) @ W2_2 + BN -> dot W_lin -> logits ----------
__global__ __launch_bounds__(256) void gemm_L2(
        const unsigned short* __restrict__ agg2h, float* __restrict__ logits,
        const float* __restrict__ W2, const float* __restrict__ b2,
        const float* __restrict__ gamma, const float* __restrict__ beta,
        const float* __restrict__ mean, const float* __restrict__ var,
        const float* __restrict__ Wl, const float* __restrict__ bl) {
    constexpr int MT = 32, LD = 36;
    __shared__ float sh[MT * LD];
    const int tid = threadIdx.x;
    const int nodeBase = blockIdx.x * MT;

    // stage: 32 nodes x 32 bf16; one uint2 (4 bf16) per thread
    {
        int row = tid >> 3, c = tid & 7;
        int node = nodeBase + row;
        uint2 v = (node < NN) ? ((const uint2*)agg2h)[(size_t)node * 8 + c]
                              : make_uint2(0u, 0u);
        sh[row * LD + c * 4 + 0] = BF2F_LO(v.x);
        sh[row * LD + c * 4 + 1] = BF2F_HI(v.x);
        sh[row * LD + c * 4 + 2] = BF2F_LO(v.y);
        sh[row * LD + c * 4 + 3] = BF2F_HI(v.y);
    }
    __syncthreads();

    // GEMM: 32->32 (W2_2) + BN (no relu), dot W_lin. CT=8, RT=32
    const int colid = tid % 8, rowid = tid / 8;
    const int c0 = colid * 4, r0 = rowid;
    float acc[4];
    {
        float4 bv = *(const float4*)&b2[c0];
        acc[0] = bv.x; acc[1] = bv.y; acc[2] = bv.z; acc[3] = bv.w;
        #pragma unroll
        for (int k4 = 0; k4 < 8; k4++) {
            float4 w[4];
            #pragma unroll
            for (int kk = 0; kk < 4; kk++)
                w[kk] = *(const float4*)&W2[(k4 * 4 + kk) * 32 + c0];
            float4 a = *(const float4*)&sh[r0 * LD + k4 * 4];
            const float av[4] = {a.x, a.y, a.z, a.w};
            #pragma unroll
            for (int kk = 0; kk < 4; kk++) {
                const float* wp = (const float*)&w[kk];
                #pragma unroll
                for (int j = 0; j < 4; j++)
                    acc[j] = fmaf(av[kk], wp[j], acc[j]);
            }
        }
    }
    float4 gv = *(const float4*)&gamma[c0];
    float4 bev = *(const float4*)&beta[c0];
    float4 mv = *(const float4*)&mean[c0];
    float4 vv = *(const float4*)&var[c0];
    float4 wl = *(const float4*)&Wl[c0];
    float p = 0.f;
    {
        const float* gp = (const float*)&gv; const float* bp = (const float*)&bev;
        const float* mp = (const float*)&mv; const float* vp = (const float*)&vv;
        const float* wp = (const float*)&wl;
        #pragma unroll
        for (int j = 0; j < 4; j++) {
            float sc = gp[j] * (1.0f / sqrtf(vp[j] + 1e-5f));
            float y = (acc[j] - mp[j]) * sc + bp[j];
            p = fmaf(y, wp[j], p);
        }
    }
    p += __shfl_xor(p, 1);
    p += __shfl_xor(p, 2);
    p += __shfl_xor(p, 4);
    int node = nodeBase + r0;
    if ((tid & 7) == 0 && node < NN)
        logits[node] = (p + bl[0]) * 0.2f;
}

// ---------- head ----------
__global__ __launch_bounds__(256) void seg_softmax(
        const float* __restrict__ logits, const int* __restrict__ gstart,
        float* __restrict__ out) {
    __shared__ float slog[1024];
    __shared__ float sred[4];
    __shared__ float sbc[2];
    int g = blockIdx.x;
    int beg = gstart[g], end = gstart[g + 1];
    int cnt = end - beg;
    int t = threadIdx.x;
    if (cnt <= 0) return;
    bool fits = (cnt <= 1024);

    float lmax = -3.402823466e+38f;
    for (int i = t; i < cnt; i += 256) {
        float lg = logits[beg + i];
        if (fits) slog[i] = lg;
        lmax = fmaxf(lmax, lg);
    }
    #pragma unroll
    for (int off = 32; off > 0; off >>= 1)
        lmax = fmaxf(lmax, __shfl_down(lmax, off));
    if ((t & 63) == 0) sred[t >> 6] = lmax;
    __syncthreads();
    if (t == 0) sbc[0] = fmaxf(fmaxf(sred[0], sred[1]), fmaxf(sred[2], sred[3]));
    __syncthreads();
    float gm = sbc[0];

    float lsum = 0.f;
    for (int i = t; i < cnt; i += 256) {
        float lg = fits ? slog[i] : logits[beg + i];
        float e = expf(lg - gm);
        if (fits) slog[i] = e;
        lsum += e;
    }
    #pragma unroll
    for (int off = 32; off > 0; off >>= 1)
        lsum += __shfl_down(lsum, off);
    __syncthreads();
    if ((t & 63) == 0) sred[t >> 6] = lsum;
    __syncthreads();
    if (t == 0) sbc[1] = (sred[0] + sred[1]) + (sred[2] + sred[3]);
    __syncthreads();
    float inv = 1.0f / sbc[1];

    for (int i = t; i < cnt; i += 256) {
        float e = fits ? slog[i] : expf(logits[beg + i] - gm);
        out[beg + i] = e * inv;
    }
}

// ---------- launch ----------
extern "C" void kernel_launch(void* const* d_in, const int* in_sizes, int n_in,
                              void* d_out, int out_size, void* d_ws, size_t ws_size,
                              hipStream_t stream) {
    const float* x    = (const float*)d_in[0];
    const int*   ei   = (const int*)d_in[1];
    const int*   srcI = ei;
    const int*   dstI = ei + NE;
    const int*   batch = (const int*)d_in[2];

    const float* P[29];
    for (int i = 0; i < 29; i++) P[i] = (const float*)d_in[i];
    const float* Wlin = P[27];
    const float* blin = P[28];

    unsigned short* xh  = (unsigned short*)d_ws;       // N x 128 bf16
    unsigned short* z1h = xh + (size_t)NN * 128;       // N x 64 bf16
    unsigned short* z2h = z1h + (size_t)NN * 64;       // N x 32 bf16
    float* logits = (float*)(z2h + (size_t)NN * 32);   // N
    int* gstart = (int*)(logits + NN);                 // NG+1
    int* rowptr = gstart + NG + 1;                     // N+1
    int* cnt1   = rowptr + NN + 1;                     // CB x NBK
    int* off1   = cnt1 + CB * NBK;                     // CB x NBK
    int* bstart = off1 + CB * NBK;                     // NBK+1
    uintptr_t tal = ((uintptr_t)(bstart + NBK + 1) + 15) & ~(uintptr_t)15;
    int2* tmp   = (int2*)tal;                          // NE int2 (bucket-major)
    int* esrc   = (int*)(tmp + NE);                    // E
    uintptr_t pal = ((uintptr_t)(esrc + NE) + 255) & ~(uintptr_t)255;
    unsigned short* aggh  = (unsigned short*)pal;      // N x 128 bf16
    unsigned short* W1t   = aggh + (size_t)NN * 128;   // 128x128 bf16 [n][k]
    unsigned short* W2t   = W1t + 16384;               // 128x128 bf16 [n][k]
    unsigned short* W3t   = W2t + 16384;               // 64x128 bf16 [n][k]
    unsigned short* W21t  = W3t + 8192;                // 64x64 bf16 [n][k]
    unsigned short* W12t  = W21t + 4096;               // 32x64 bf16 [n][k]
    unsigned short* agg1h = W12t + 2048;               // N x 64 bf16
    unsigned short* agg2h = agg1h + (size_t)NN * 64;   // N x 32 bf16
    float* outp = (float*)d_out;

    const int TB = 256;

    // CSR build: zero global atomics (LDS-histogram bucket sort)
    conv_count<<<(N4 + TB - 1) / TB, TB, 0, stream>>>(
        (const float4*)x, (ushort4*)xh, (const int4*)dstI, cnt1);
    scan_buckets<<<1, 256, 0, stream>>>(cnt1, off1, bstart, rowptr);
    scatter1<<<CB, 256, 0, stream>>>(
        (const int4*)srcI, (const int4*)dstI, off1, tmp);
    bucket_build<<<NBK, 256, 0, stream>>>(tmp, bstart, batch, rowptr, gstart, esrc,
        P[3], P[5], P[11], P[13], P[19], W1t, W2t, W3t, W21t, W12t);

    const int GB   = (NN + 3) / 4;     // gathers: 1 wave/node
    const int FB64 = (NN + 63) / 64;
    const int FB32 = (NN + 31) / 32;

    gather_L0<<<GB, 256, 0, stream>>>(xh, esrc, rowptr, aggh);
    gemm_L0<<<FB64, 256, 0, stream>>>(aggh, z1h, W1t, W2t, W3t,
        P[4], P[6], P[7], P[8], P[9], P[10]);
    gather_L1<<<GB, 256, 0, stream>>>(z1h, esrc, rowptr, P[12], agg1h);
    gemm_L1<<<FB64, 256, 0, stream>>>(agg1h, z2h, W21t, W12t,
        P[14], P[15], P[16], P[17], P[18]);
    gather_L2<<<GB, 256, 0, stream>>>(z2h, esrc, rowptr, P[20], agg2h);
    gemm_L2<<<FB32, 256, 0, stream>>>(agg2h, logits,
        P[21], P[22], P[23], P[24], P[25], P[26], Wlin, blin);

    seg_softmax<<<NG, 256, 0, stream>>>(logits, gstart, outp);
}

// Round 11
// 261.034 us; speedup vs baseline: 1.1028x; 1.0048x over previous
//
#include <hip/hip_runtime.h>

#define NN 50000
#define NE 800000
#define NG 256
#define N4 (NN * 128 / 4)       // float4 count of x (1.6M)
#define NQ (NE / 4)             // edge quads (200000)
#define CB 64                   // count/scatter blocks
#define QPB (NQ / CB)           // 3125 quads per block (exact)
#define NBK 196                 // dst>>8 buckets (50000/256 rounded up)

typedef __attribute__((ext_vector_type(8))) short bf16x8;
typedef __attribute__((ext_vector_type(4))) float f32x4;

// ---------- bf16 helpers ----------
__device__ __forceinline__ unsigned short f2bf_rne(float f) {
    unsigned u = __float_as_uint(f);
    u += 0x7fffu + ((u >> 16) & 1u);   // round-to-nearest-even
    return (unsigned short)(u >> 16);
}
#define BF2F_LO(u) __uint_as_float((u) << 16)
#define BF2F_HI(u) __uint_as_float((u) & 0xffff0000u)

// ---------- pass 1: x->bf16 convert + per-block LDS bucket histogram ----------
// NO global atomics: blocks 0..CB-1 count dst>>8 into LDS, write cnt1[b][k].
__global__ void conv_count(const float4* __restrict__ x, ushort4* __restrict__ xh,
                           const int4* __restrict__ dst4, int* __restrict__ cnt1) {
    __shared__ int hist[NBK];
    int i = blockIdx.x * 256 + threadIdx.x;
    if (i < N4) {
        float4 v = x[i];
        ushort4 o;
        o.x = f2bf_rne(v.x); o.y = f2bf_rne(v.y);
        o.z = f2bf_rne(v.z); o.w = f2bf_rne(v.w);
        xh[i] = o;
    }
    if (blockIdx.x < CB) {
        int t = threadIdx.x;
        if (t < NBK) hist[t] = 0;
        __syncthreads();
        int qb = blockIdx.x * QPB;
        for (int qi = t; qi < QPB; qi += 256) {
            int4 d = dst4[qb + qi];
            atomicAdd(&hist[d.x >> 8], 1);
            atomicAdd(&hist[d.y >> 8], 1);
            atomicAdd(&hist[d.z >> 8], 1);
            atomicAdd(&hist[d.w >> 8], 1);
        }
        __syncthreads();
        if (t < NBK) cnt1[blockIdx.x * NBK + t] = hist[t];
    }
}

// ---------- pass 2: scatter edges to bucket-major tmp (per-block private scan of cnt1) ----------
// tmp packs (dst&255)<<16 | src  (both fit 16 bits: src<50000<65536, dst&255<256)
__global__ __launch_bounds__(256) void scatter1(
        const int4* __restrict__ src4, const int4* __restrict__ dst4,
        const int* __restrict__ cnt1, unsigned* __restrict__ tmp) {
    __shared__ int c[CB * NBK];   // 50176 B
    __shared__ int sh[256];
    __shared__ int curs[256];
    int t = threadIdx.x;
    for (int idx = t; idx < CB * NBK; idx += 256) c[idx] = cnt1[idx];
    __syncthreads();
    int myoff = 0, tv = 0;
    if (t < NBK) {
        int run = 0;
        for (int b = 0; b < CB; b++) {
            if (b == (int)blockIdx.x) myoff = run;
            run += c[b * NBK + t];
        }
        tv = run;                 // column total for bucket t
    }
    sh[t] = tv;
    __syncthreads();
    int v = sh[t];
    #pragma unroll
    for (int off = 1; off < 256; off <<= 1) {
        int add = (t >= off) ? sh[t - off] : 0;
        __syncthreads();
        sh[t] += add;
        __syncthreads();
    }
    int excl = sh[t] - v;         // bstart[t]
    if (t < NBK) curs[t] = excl + myoff;
    __syncthreads();
    int qb = blockIdx.x * QPB;
    for (int qi = t; qi < QPB; qi += 256) {
        int4 s = src4[qb + qi];
        int4 d = dst4[qb + qi];
        int p0 = atomicAdd(&curs[d.x >> 8], 1);
        int p1 = atomicAdd(&curs[d.y >> 8], 1);
        int p2 = atomicAdd(&curs[d.z >> 8], 1);
        int p3 = atomicAdd(&curs[d.w >> 8], 1);
        tmp[p0] = (unsigned)s.x | ((unsigned)(d.x & 255) << 16);
        tmp[p1] = (unsigned)s.y | ((unsigned)(d.y & 255) << 16);
        tmp[p2] = (unsigned)s.z | ((unsigned)(d.z & 255) << 16);
        tmp[p3] = (unsigned)s.w | ((unsigned)(d.w & 255) << 16);
    }
}

// ---------- pass 3: per-bucket CSR finalize: rowptr + gstart + esrc ----------
// (+ weight transpose/convert side-work: 196 blocks x 256 >= 30720 threads)
__global__ __launch_bounds__(256) void bucket_build(
        const unsigned* __restrict__ tmp, const int* __restrict__ cnt1,
        const int* __restrict__ batch, int* __restrict__ rowptr,
        int* __restrict__ gstart, int* __restrict__ esrc,
        const float* __restrict__ W1, const float* __restrict__ W2,
        const float* __restrict__ W3,
        const float* __restrict__ W21, const float* __restrict__ W12,
        unsigned short* __restrict__ W1t, unsigned short* __restrict__ W2t,
        unsigned short* __restrict__ W3t, unsigned short* __restrict__ W21t,
        unsigned short* __restrict__ W12t) {
    int gidx = blockIdx.x * 256 + threadIdx.x;
    if (gidx < 16384) {
        int n = gidx >> 7, k = gidx & 127;
        W1t[gidx] = f2bf_rne(W1[k * 128 + n]);
        W2t[gidx] = f2bf_rne(W2[k * 128 + n]);
    } else if (gidx < 24576) {
        int i2 = gidx - 16384;
        int n = i2 >> 7, k = i2 & 127;
        W3t[i2] = f2bf_rne(W3[k * 64 + n]);
    } else if (gidx < 28672) {
        int i3 = gidx - 24576;
        int n = i3 >> 6, k = i3 & 63;
        W21t[i3] = f2bf_rne(W21[k * 64 + n]);
    } else if (gidx < 30720) {
        int i4 = gidx - 28672;
        int n = i4 >> 6, k = i4 & 63;
        W12t[i4] = f2bf_rne(W12[k * 32 + n]);
    }

    __shared__ int c[CB * NBK];   // 50176 B
    __shared__ int tot[256];
    __shared__ int pre[256];
    __shared__ int hist[256];
    __shared__ int sh[256];
    __shared__ int curs[256];
    int t = threadIdx.x, k1 = blockIdx.x;

    // private scan of cnt1 -> bucket start b0 and count cnt
    for (int idx = t; idx < CB * NBK; idx += 256) c[idx] = cnt1[idx];
    __syncthreads();
    int tv = 0;
    if (t < NBK) {
        int run = 0;
        for (int b = 0; b < CB; b++) run += c[b * NBK + t];
        tv = run;
    }
    tot[t] = tv;
    sh[t] = tv;
    __syncthreads();
    int v0 = sh[t];
    #pragma unroll
    for (int off = 1; off < 256; off <<= 1) {
        int add = (t >= off) ? sh[t - off] : 0;
        __syncthreads();
        sh[t] += add;
        __syncthreads();
    }
    pre[t] = sh[t] - v0;
    __syncthreads();
    const int b0 = pre[k1];
    const int cnt = tot[k1];

    // per-bucket histogram of dst&255 -> rowptr + esrc scatter
    hist[t] = 0;
    __syncthreads();
    for (int e = t; e < cnt; e += 256) {
        unsigned pk = tmp[b0 + e];
        atomicAdd(&hist[pk >> 16], 1);
    }
    __syncthreads();
    int v = hist[t];
    sh[t] = v;
    __syncthreads();
    #pragma unroll
    for (int off = 1; off < 256; off <<= 1) {
        int add = (t >= off) ? sh[t - off] : 0;
        __syncthreads();
        sh[t] += add;
        __syncthreads();
    }
    int excl = sh[t] - v;
    int node = k1 * 256 + t;
    if (node < NN) {
        rowptr[node] = b0 + excl;
        int b = batch[node];
        if (node == 0) {
            for (int g = 0; g <= b; g++) gstart[g] = 0;
        } else {
            int p = batch[node - 1];
            for (int g = p + 1; g <= b; g++) gstart[g] = node;
        }
        if (node == NN - 1) {
            for (int g = b + 1; g <= NG; g++) gstart[g] = NN;
        }
    }
    if (k1 == 0 && t == 0) rowptr[NN] = NE;
    curs[t] = b0 + excl;
    __syncthreads();
    for (int e = t; e < cnt; e += 256) {
        unsigned pk = tmp[b0 + e];
        int slot = atomicAdd(&curs[pk >> 16], 1);
        esrc[slot] = (int)(pk & 0xffffu);
    }
}

// ---------- bf16 wave-cooperative gathers ----------
// C lane-chunks per row, EPI = 64/C edges per pass; 4x/2x/1x unroll keeps
// up to 4 independent loads in flight.

// 16B-lane variant (rows = 256B): x (128 cols)
template <int C4>
__device__ __forceinline__ void gather_bf16(const uint4* __restrict__ x4,
                                            const int* __restrict__ esrc,
                                            int beg, int cnt, int node, int lane,
                                            float* a /* [8] */) {
    constexpr int EPI = 64 / C4;
    const int chunk = lane & (C4 - 1);
    const int esl   = lane / C4;
    #define ACC_U4(u) do { \
        a[0] += BF2F_LO((u).x); a[1] += BF2F_HI((u).x); \
        a[2] += BF2F_LO((u).y); a[3] += BF2F_HI((u).y); \
        a[4] += BF2F_LO((u).z); a[5] += BF2F_HI((u).z); \
        a[6] += BF2F_LO((u).w); a[7] += BF2F_HI((u).w); } while (0)
    if (esl == 0) { uint4 u = x4[(size_t)node * C4 + chunk]; ACC_U4(u); }
    for (int c = 0; c < cnt; c += 64) {
        int take = min(64, cnt - c);
        int myi = (lane < take) ? esrc[beg + c + lane] : 0;
        int i = 0;
        for (; i + 4 * EPI <= take; i += 4 * EPI) {
            int s0 = __shfl(myi, i + esl);
            int s1 = __shfl(myi, i + EPI + esl);
            int s2 = __shfl(myi, i + 2 * EPI + esl);
            int s3 = __shfl(myi, i + 3 * EPI + esl);
            uint4 u0 = x4[(size_t)s0 * C4 + chunk];
            uint4 u1 = x4[(size_t)s1 * C4 + chunk];
            uint4 u2 = x4[(size_t)s2 * C4 + chunk];
            uint4 u3 = x4[(size_t)s3 * C4 + chunk];
            ACC_U4(u0); ACC_U4(u1); ACC_U4(u2); ACC_U4(u3);
        }
        if (i + 2 * EPI <= take) {
            int s0 = __shfl(myi, i + esl);
            int s1 = __shfl(myi, i + EPI + esl);
            uint4 u0 = x4[(size_t)s0 * C4 + chunk];
            uint4 u1 = x4[(size_t)s1 * C4 + chunk];
            ACC_U4(u0); ACC_U4(u1);
            i += 2 * EPI;
        }
        if (i + EPI <= take) {
            int s = __shfl(myi, i + esl);
            uint4 u = x4[(size_t)s * C4 + chunk];
            ACC_U4(u);
            i += EPI;
        }
        int rem = take - i;
        if (rem > 0) {
            int s = __shfl(myi, i + ((esl < rem) ? esl : 0));
            uint4 u = x4[(size_t)s * C4 + chunk];
            if (esl < rem) ACC_U4(u);
        }
    }
    #undef ACC_U4
    for (int off = 32; off >= C4; off >>= 1) {
        #pragma unroll
        for (int q = 0; q < 8; q++)
            a[q] += __shfl_xor(a[q], off);
    }
}

// 8B-lane variant (rows = 128B): z1 (64 cols). C=16, EPI=4.
template <int C>
__device__ __forceinline__ void gather_bf16_u2(const uint2* __restrict__ x2,
                                               const int* __restrict__ esrc,
                                               int beg, int cnt, int node, int lane,
                                               float* a /* [4] */) {
    constexpr int EPI = 64 / C;
    const int chunk = lane & (C - 1);
    const int esl   = lane / C;
    #define ACC_U2(u) do { \
        a[0] += BF2F_LO((u).x); a[1] += BF2F_HI((u).x); \
        a[2] += BF2F_LO((u).y); a[3] += BF2F_HI((u).y); } while (0)
    if (esl == 0) { uint2 u = x2[(size_t)node * C + chunk]; ACC_U2(u); }
    for (int c = 0; c < cnt; c += 64) {
        int take = min(64, cnt - c);
        int myi = (lane < take) ? esrc[beg + c + lane] : 0;
        int i = 0;
        for (; i + 4 * EPI <= take; i += 4 * EPI) {
            int s0 = __shfl(myi, i + esl);
            int s1 = __shfl(myi, i + EPI + esl);
            int s2 = __shfl(myi, i + 2 * EPI + esl);
            int s3 = __shfl(myi, i + 3 * EPI + esl);
            uint2 u0 = x2[(size_t)s0 * C + chunk];
            uint2 u1 = x2[(size_t)s1 * C + chunk];
            uint2 u2 = x2[(size_t)s2 * C + chunk];
            uint2 u3 = x2[(size_t)s3 * C + chunk];
            ACC_U2(u0); ACC_U2(u1); ACC_U2(u2); ACC_U2(u3);
        }
        if (i + 2 * EPI <= take) {
            int s0 = __shfl(myi, i + esl);
            int s1 = __shfl(myi, i + EPI + esl);
            uint2 u0 = x2[(size_t)s0 * C + chunk];
            uint2 u1 = x2[(size_t)s1 * C + chunk];
            ACC_U2(u0); ACC_U2(u1);
            i += 2 * EPI;
        }
        if (i + EPI <= take) {
            int s = __shfl(myi, i + esl);
            uint2 u = x2[(size_t)s * C + chunk];
            ACC_U2(u);
            i += EPI;
        }
        int rem = take - i;
        if (rem > 0) {
            int s = __shfl(myi, i + ((esl < rem) ? esl : 0));
            uint2 u = x2[(size_t)s * C + chunk];
            if (esl < rem) ACC_U2(u);
        }
    }
    #undef ACC_U2
    for (int off = 32; off >= C; off >>= 1) {
        #pragma unroll
        for (int q = 0; q < 4; q++)
            a[q] += __shfl_xor(a[q], off);
    }
}

// 4B-lane variant (rows = 64B): z2 (32 cols). C=16, EPI=4.
template <int C>
__device__ __forceinline__ void gather_bf16_u1(const unsigned* __restrict__ x1,
                                               const int* __restrict__ esrc,
                                               int beg, int cnt, int node, int lane,
                                               float* a /* [2] */) {
    constexpr int EPI = 64 / C;
    const int chunk = lane & (C - 1);
    const int esl   = lane / C;
    #define ACC_U1(u) do { \
        a[0] += BF2F_LO(u); a[1] += BF2F_HI(u); } while (0)
    if (esl == 0) { unsigned u = x1[(size_t)node * C + chunk]; ACC_U1(u); }
    for (int c = 0; c < cnt; c += 64) {
        int take = min(64, cnt - c);
        int myi = (lane < take) ? esrc[beg + c + lane] : 0;
        int i = 0;
        for (; i + 4 * EPI <= take; i += 4 * EPI) {
            int s0 = __shfl(myi, i + esl);
            int s1 = __shfl(myi, i + EPI + esl);
            int s2 = __shfl(myi, i + 2 * EPI + esl);
            int s3 = __shfl(myi, i + 3 * EPI + esl);
            unsigned u0 = x1[(size_t)s0 * C + chunk];
            unsigned u1 = x1[(size_t)s1 * C + chunk];
            unsigned u2 = x1[(size_t)s2 * C + chunk];
            unsigned u3 = x1[(size_t)s3 * C + chunk];
            ACC_U1(u0); ACC_U1(u1); ACC_U1(u2); ACC_U1(u3);
        }
        if (i + 2 * EPI <= take) {
            int s0 = __shfl(myi, i + esl);
            int s1 = __shfl(myi, i + EPI + esl);
            unsigned u0 = x1[(size_t)s0 * C + chunk];
            unsigned u1 = x1[(size_t)s1 * C + chunk];
            ACC_U1(u0); ACC_U1(u1);
            i += 2 * EPI;
        }
        if (i + EPI <= take) {
            int s = __shfl(myi, i + esl);
            unsigned u = x1[(size_t)s * C + chunk];
            ACC_U1(u);
            i += EPI;
        }
        int rem = take - i;
        if (rem > 0) {
            int s = __shfl(myi, i + ((esl < rem) ? esl : 0));
            unsigned u = x1[(size_t)s * C + chunk];
            if (esl < rem) ACC_U1(u);
        }
    }
    #undef ACC_U1
    for (int off = 32; off >= C; off >>= 1) {
        #pragma unroll
        for (int q = 0; q < 2; q++)
            a[q] += __shfl_xor(a[q], off);
    }
}

// ---------- L0 gather: one wave per node -> bf16 agg ----------
__global__ __launch_bounds__(256) void gather_L0(
        const unsigned short* __restrict__ xh, const int* __restrict__ esrc,
        const int* __restrict__ rowptr, unsigned short* __restrict__ aggh /* N x 128 bf16 */) {
    const int wave = threadIdx.x >> 6, lane = threadIdx.x & 63;
    const int node = blockIdx.x * 4 + wave;
    if (node >= NN) return;
    float a[8] = {0, 0, 0, 0, 0, 0, 0, 0};
    int beg = rowptr[node], end = rowptr[node + 1];
    gather_bf16<16>((const uint4*)xh, esrc, beg, end - beg, node, lane, a);
    if (lane < 16) {
        uint4 o;
        o.x = (unsigned)f2bf_rne(a[0]) | ((unsigned)f2bf_rne(a[1]) << 16);
        o.y = (unsigned)f2bf_rne(a[2]) | ((unsigned)f2bf_rne(a[3]) << 16);
        o.z = (unsigned)f2bf_rne(a[4]) | ((unsigned)f2bf_rne(a[5]) << 16);
        o.w = (unsigned)f2bf_rne(a[6]) | ((unsigned)f2bf_rne(a[7]) << 16);
        *(uint4*)&aggh[(size_t)node * 128 + lane * 8] = o;
    }
}

// ---------- L1 gather: one wave per node; +b1, relu -> bf16 agg1 ----------
__global__ __launch_bounds__(256) void gather_L1(
        const unsigned short* __restrict__ z1h, const int* __restrict__ esrc,
        const int* __restrict__ rowptr, const float* __restrict__ b1,
        unsigned short* __restrict__ agg1h /* N x 64 bf16 */) {
    const int wave = threadIdx.x >> 6, lane = threadIdx.x & 63;
    const int node = blockIdx.x * 4 + wave;
    if (node >= NN) return;
    float a[4] = {0, 0, 0, 0};
    int beg = rowptr[node], end = rowptr[node + 1];
    gather_bf16_u2<16>((const uint2*)z1h, esrc, beg, end - beg, node, lane, a);
    if (lane < 16) {
        float4 bv = *(const float4*)&b1[lane * 4];
        uint2 o;
        o.x = (unsigned)f2bf_rne(fmaxf(a[0] + bv.x, 0.f)) |
              ((unsigned)f2bf_rne(fmaxf(a[1] + bv.y, 0.f)) << 16);
        o.y = (unsigned)f2bf_rne(fmaxf(a[2] + bv.z, 0.f)) |
              ((unsigned)f2bf_rne(fmaxf(a[3] + bv.w, 0.f)) << 16);
        *(uint2*)&agg1h[(size_t)node * 64 + lane * 4] = o;
    }
}

// ---------- L2 gather: one wave per node; +b1, relu -> bf16 agg2 ----------
__global__ __launch_bounds__(256) void gather_L2(
        const unsigned short* __restrict__ z2h, const int* __restrict__ esrc,
        const int* __restrict__ rowptr, const float* __restrict__ b1,
        unsigned short* __restrict__ agg2h /* N x 32 bf16 */) {
    const int wave = threadIdx.x >> 6, lane = threadIdx.x & 63;
    const int node = blockIdx.x * 4 + wave;
    if (node >= NN) return;
    float a[2] = {0, 0};
    int beg = rowptr[node], end = rowptr[node + 1];
    gather_bf16_u1<16>((const unsigned*)z2h, esrc, beg, end - beg, node, lane, a);
    if (lane < 16) {
        float2 bv = *(const float2*)&b1[lane * 2];
        unsigned o = (unsigned)f2bf_rne(fmaxf(a[0] + bv.x, 0.f)) |
                     ((unsigned)f2bf_rne(fmaxf(a[1] + bv.y, 0.f)) << 16);
        *(unsigned*)&agg2h[(size_t)node * 32 + lane * 2] = o;
    }
}

// ---------- L0 GEMM chain via MFMA bf16 (MT=64, 4 waves) ----------
// GEMM1: relu(agg@W1+b1) -> GEMM2: BN(.@W2+b2), relu -> GEMM3: .@W1_1 -> z1h
// MFMA 16x16x32 bf16 layouts: A[m=l&15][k=(l>>4)*8+j], B[k=(l>>4)*8+j][n=l&15],
// D[row=(l>>4)*4+r][col=l&15]  (m89-verified C/D mapping)
__global__ __launch_bounds__(256) void gemm_L0(
        const unsigned short* __restrict__ aggh, unsigned short* __restrict__ z1h,
        const unsigned short* __restrict__ W1t,  // [128n][128k] bf16
        const unsigned short* __restrict__ W2t,  // [128n][128k] bf16
        const unsigned short* __restrict__ W3t,  // [64n][128k] bf16
        const float* __restrict__ b1, const float* __restrict__ b2,
        const float* __restrict__ gamma, const float* __restrict__ beta,
        const float* __restrict__ mean, const float* __restrict__ var) {
    constexpr int MT = 64, LDA = 136;   // bf16 units; 272B row stride
    __shared__ __align__(16) unsigned short shA[MT * LDA];
    __shared__ __align__(16) unsigned short shB[MT * LDA];
    const int tid = threadIdx.x;
    const int wave = tid >> 6, lane = tid & 63;
    const int nodeBase = blockIdx.x * MT;
    const int lr = lane & 15;
    const int lg = lane >> 4;
    const int lk = lg * 8;
    const int n0 = wave * 32;

    // stage bf16 agg tile -> shA, coalesced 16B
    #pragma unroll
    for (int j = 0; j < 4; j++) {
        int f = tid + j * 256;
        int row = f >> 4, c = f & 15;
        int node = nodeBase + row;
        uint4 v = (node < NN) ? ((const uint4*)aggh)[(size_t)node * 16 + c]
                              : make_uint4(0u, 0u, 0u, 0u);
        *(uint4*)&shA[row * LDA + c * 8] = v;
    }
    __syncthreads();

    f32x4 acc[4][2];

    // GEMM1: h1 = relu(A @ W1 + b1); wave owns cols [n0, n0+32)
    {
        float bv0 = b1[n0 + lr], bv1 = b1[n0 + 16 + lr];
        #pragma unroll
        for (int m = 0; m < 4; m++) {
            f32x4 c0 = {bv0, bv0, bv0, bv0};
            f32x4 c1 = {bv1, bv1, bv1, bv1};
            acc[m][0] = c0; acc[m][1] = c1;
        }
        #pragma unroll
        for (int ks = 0; ks < 4; ks++) {
            const int k0 = ks * 32 + lk;
            bf16x8 wb0 = *(const bf16x8*)&W1t[(n0 + lr) * 128 + k0];
            bf16x8 wb1 = *(const bf16x8*)&W1t[(n0 + 16 + lr) * 128 + k0];
            #pragma unroll
            for (int m = 0; m < 4; m++) {
                bf16x8 af = *(const bf16x8*)&shA[(m * 16 + lr) * LDA + k0];
                acc[m][0] = __builtin_amdgcn_mfma_f32_16x16x32_bf16(af, wb0, acc[m][0], 0, 0, 0);
                acc[m][1] = __builtin_amdgcn_mfma_f32_16x16x32_bf16(af, wb1, acc[m][1], 0, 0, 0);
            }
        }
    }
    #pragma unroll
    for (int m = 0; m < 4; m++) {
        #pragma unroll
        for (int nt = 0; nt < 2; nt++) {
            #pragma unroll
            for (int r = 0; r < 4; r++) {
                shB[(m * 16 + lg * 4 + r) * LDA + (n0 + nt * 16 + lr)] =
                    f2bf_rne(fmaxf(acc[m][nt][r], 0.f));
            }
        }
    }
    __syncthreads();

    // GEMM2: h2 = relu(BN(h1 @ W2 + b2))
    {
        float bv0 = b2[n0 + lr], bv1 = b2[n0 + 16 + lr];
        #pragma unroll
        for (int m = 0; m < 4; m++) {
            f32x4 c0 = {bv0, bv0, bv0, bv0};
            f32x4 c1 = {bv1, bv1, bv1, bv1};
            acc[m][0] = c0; acc[m][1] = c1;
        }
        #pragma unroll
        for (int ks = 0; ks < 4; ks++) {
            const int k0 = ks * 32 + lk;
            bf16x8 wb0 = *(const bf16x8*)&W2t[(n0 + lr) * 128 + k0];
            bf16x8 wb1 = *(const bf16x8*)&W2t[(n0 + 16 + lr) * 128 + k0];
            #pragma unroll
            for (int m = 0; m < 4; m++) {
                bf16x8 af = *(const bf16x8*)&shB[(m * 16 + lr) * LDA + k0];
                acc[m][0] = __builtin_amdgcn_mfma_f32_16x16x32_bf16(af, wb0, acc[m][0], 0, 0, 0);
                acc[m][1] = __builtin_amdgcn_mfma_f32_16x16x32_bf16(af, wb1, acc[m][1], 0, 0, 0);
            }
        }
    }
    float s0 = gamma[n0 + lr]      * (1.0f / sqrtf(var[n0 + lr] + 1e-5f));
    float t0 = beta[n0 + lr]       - mean[n0 + lr] * s0;
    float s1 = gamma[n0 + 16 + lr] * (1.0f / sqrtf(var[n0 + 16 + lr] + 1e-5f));
    float t1 = beta[n0 + 16 + lr]  - mean[n0 + 16 + lr] * s1;
    #pragma unroll
    for (int m = 0; m < 4; m++) {
        #pragma unroll
        for (int nt = 0; nt < 2; nt++) {
            float sc = nt ? s1 : s0, sf = nt ? t1 : t0;
            #pragma unroll
            for (int r = 0; r < 4; r++) {
                float y = fmaxf(fmaf(acc[m][nt][r], sc, sf), 0.f);
                shA[(m * 16 + lg * 4 + r) * LDA + (n0 + nt * 16 + lr)] = f2bf_rne(y);
            }
        }
    }
    __syncthreads();

    // GEMM3: z1 = h2 @ W1_1; wave owns cols [wave*16, +16)
    f32x4 a3[4];
    #pragma unroll
    for (int m = 0; m < 4; m++) {
        f32x4 z = {0.f, 0.f, 0.f, 0.f};
        a3[m] = z;
    }
    #pragma unroll
    for (int ks = 0; ks < 4; ks++) {
        const int k0 = ks * 32 + lk;
        bf16x8 wb = *(const bf16x8*)&W3t[(wave * 16 + lr) * 128 + k0];
        #pragma unroll
        for (int m = 0; m < 4; m++) {
            bf16x8 af = *(const bf16x8*)&shA[(m * 16 + lr) * LDA + k0];
            a3[m] = __builtin_amdgcn_mfma_f32_16x16x32_bf16(af, wb, a3[m], 0, 0, 0);
        }
    }
    #pragma unroll
    for (int m = 0; m < 4; m++) {
        #pragma unroll
        for (int r = 0; r < 4; r++) {
            int node = nodeBase + m * 16 + lg * 4 + r;
            if (node < NN)
                z1h[(size_t)node * 64 + wave * 16 + lr] = f2bf_rne(a3[m][r]);
        }
    }
}

// ---------- L1 GEMM chain via MFMA (MT=64, 4 waves): agg1(64,relu'd) @ W2_1+BN+relu -> @W1_2 -> z2h ----------
__global__ __launch_bounds__(256) void gemm_L1(
        const unsigned short* __restrict__ agg1h, unsigned short* __restrict__ z2h,
        const unsigned short* __restrict__ W21t,  // [64n][64k] bf16
        const unsigned short* __restrict__ W12t,  // [32n][64k] bf16
        const float* __restrict__ b2, const float* __restrict__ gamma,
        const float* __restrict__ beta, const float* __restrict__ mean,
        const float* __restrict__ var) {
    constexpr int MT = 64, LDA = 72;   // bf16; 144B row stride (2-way bank alias, free)
    __shared__ __align__(16) unsigned short shA[MT * LDA];
    __shared__ __align__(16) unsigned short shB[MT * LDA];
    const int tid = threadIdx.x;
    const int wave = tid >> 6, lane = tid & 63;
    const int nodeBase = blockIdx.x * MT;
    const int lr = lane & 15;
    const int lg = lane >> 4;
    const int lk = lg * 8;
    const int n0 = wave * 16;       // GEMM_A output-column base

    // stage agg1 tile (bias+relu already applied by gather_L1)
    #pragma unroll
    for (int j = 0; j < 2; j++) {
        int f = tid + j * 256;              // 512 uint4 (8 per row)
        int row = f >> 3, c = f & 7;
        int node = nodeBase + row;
        uint4 v = (node < NN) ? ((const uint4*)agg1h)[(size_t)node * 8 + c]
                              : make_uint4(0u, 0u, 0u, 0u);
        *(uint4*)&shA[row * LDA + c * 8] = v;
    }
    __syncthreads();

    // GEMM_A: h2 = relu(BN(A @ W2_1 + b2)); wave owns cols [n0, n0+16)
    f32x4 acc[4];
    {
        float bv = b2[n0 + lr];
        #pragma unroll
        for (int m = 0; m < 4; m++) {
            f32x4 c0 = {bv, bv, bv, bv};
            acc[m] = c0;
        }
        #pragma unroll
        for (int ks = 0; ks < 2; ks++) {
            const int k0 = ks * 32 + lk;
            bf16x8 wb = *(const bf16x8*)&W21t[(n0 + lr) * 64 + k0];
            #pragma unroll
            for (int m = 0; m < 4; m++) {
                bf16x8 af = *(const bf16x8*)&shA[(m * 16 + lr) * LDA + k0];
                acc[m] = __builtin_amdgcn_mfma_f32_16x16x32_bf16(af, wb, acc[m], 0, 0, 0);
            }
        }
    }
    float sc = gamma[n0 + lr] * (1.0f / sqrtf(var[n0 + lr] + 1e-5f));
    float sf = beta[n0 + lr] - mean[n0 + lr] * sc;
    #pragma unroll
    for (int m = 0; m < 4; m++) {
        #pragma unroll
        for (int r = 0; r < 4; r++) {
            float y = fmaxf(fmaf(acc[m][r], sc, sf), 0.f);
            shB[(m * 16 + lg * 4 + r) * LDA + (n0 + lr)] = f2bf_rne(y);
        }
    }
    __syncthreads();

    // GEMM_B: z2 = h2 @ W1_2 (64->32). wave: rows [(w>>1)*32,+32), cols [(w&1)*16,+16)
    const int rh = (wave >> 1) * 32, ch = (wave & 1) * 16;
    f32x4 a3[2];
    {
        f32x4 z = {0.f, 0.f, 0.f, 0.f};
        a3[0] = z; a3[1] = z;
    }
    #pragma unroll
    for (int ks = 0; ks < 2; ks++) {
        const int k0 = ks * 32 + lk;
        bf16x8 wb = *(const bf16x8*)&W12t[(ch + lr) * 64 + k0];
        #pragma unroll
        for (int m = 0; m < 2; m++) {
            bf16x8 af = *(const bf16x8*)&shB[(rh + m * 16 + lr) * LDA + k0];
            a3[m] = __builtin_amdgcn_mfma_f32_16x16x32_bf16(af, wb, a3[m], 0, 0, 0);
        }
    }
    #pragma unroll
    for (int m = 0; m < 2; m++) {
        #pragma unroll
        for (int r = 0; r < 4; r++) {
            int node = nodeBase + rh + m * 16 + lg * 4 + r;
            if (node < NN)
                z2h[(size_t)node * 32 + ch + lr] = f2bf_rne(a3[m][r]);
        }
    }
}

// ---------- L2 GEMM (MT=32): agg2(32,relu'd) @ W2_2 + BN -> dot W_lin -> logits ----------
__global__ __launch_bounds__(256) void gemm_L2(
        const unsigned short* __restrict__ agg2h, float* __restrict__ logits,
        const float* __restrict__ W2, const float* __restrict__ b2,
        const float* __restrict__ gamma, const float* __restrict__ beta,
        const float* __restrict__ mean, const float* __restrict__ var,
        const float* __restrict__ Wl, const float* __restrict__ bl) {
    constexpr int MT = 32, LD = 36;
    __shared__ float sh[MT * LD];
    const int tid = threadIdx.x;
    const int nodeBase = blockIdx.x * MT;

    // stage: 32 nodes x 32 bf16; one uint2 (4 bf16) per thread
    {
        int row = tid >> 3, c = tid & 7;
        int node = nodeBase + row;
        uint2 v = (node < NN) ? ((const uint2*)agg2h)[(size_t)node * 8 + c]
                              : make_uint2(0u, 0u);
        sh[row * LD + c * 4 + 0] = BF2F_LO(v.x);
        sh[row * LD + c * 4 + 1] = BF2F_HI(v.x);
        sh[row * LD + c * 4 + 2] = BF2F_LO(v.y);
        sh[row * LD + c * 4 + 3] = BF2F_HI(v.y);
    }
    __syncthreads();

    // GEMM: 32->32 (W2_2) + BN (no relu), dot W_lin. CT=8, RT=32
    const int colid = tid % 8, rowid = tid / 8;
    const int c0 = colid * 4, r0 = rowid;
    float acc[4];
    {
        float4 bv = *(const float4*)&b2[c0];
        acc[0] = bv.x; acc[1] = bv.y; acc[2] = bv.z; acc[3] = bv.w;
        #pragma unroll
        for (int k4 = 0; k4 < 8; k4++) {
            float4 w[4];
            #pragma unroll
            for (int kk = 0; kk < 4; kk++)
                w[kk] = *(const float4*)&W2[(k4 * 4 + kk) * 32 + c0];
            float4 a = *(const float4*)&sh[r0 * LD + k4 * 4];
            const float av[4] = {a.x, a.y, a.z, a.w};
            #pragma unroll
            for (int kk = 0; kk < 4; kk++) {
                const float* wp = (const float*)&w[kk];
                #pragma unroll
                for (int j = 0; j < 4; j++)
                    acc[j] = fmaf(av[kk], wp[j], acc[j]);
            }
        }
    }
    float4 gv = *(const float4*)&gamma[c0];
    float4 bev = *(const float4*)&beta[c0];
    float4 mv = *(const float4*)&mean[c0];
    float4 vv = *(const float4*)&var[c0];
    float4 wl = *(const float4*)&Wl[c0];
    float p = 0.f;
    {
        const float* gp = (const float*)&gv; const float* bp = (const float*)&bev;
        const float* mp = (const float*)&mv; const float* vp = (const float*)&vv;
        const float* wp = (const float*)&wl;
        #pragma unroll
        for (int j = 0; j < 4; j++) {
            float sc = gp[j] * (1.0f / sqrtf(vp[j] + 1e-5f));
            float y = (acc[j] - mp[j]) * sc + bp[j];
            p = fmaf(y, wp[j], p);
        }
    }
    p += __shfl_xor(p, 1);
    p += __shfl_xor(p, 2);
    p += __shfl_xor(p, 4);
    int node = nodeBase + r0;
    if ((tid & 7) == 0 && node < NN)
        logits[node] = (p + bl[0]) * 0.2f;
}

// ---------- head ----------
__global__ __launch_bounds__(256) void seg_softmax(
        const float* __restrict__ logits, const int* __restrict__ gstart,
        float* __restrict__ out) {
    __shared__ float slog[1024];
    __shared__ float sred[4];
    __shared__ float sbc[2];
    int g = blockIdx.x;
    int beg = gstart[g], end = gstart[g + 1];
    int cnt = end - beg;
    int t = threadIdx.x;
    if (cnt <= 0) return;
    bool fits = (cnt <= 1024);

    float lmax = -3.402823466e+38f;
    for (int i = t; i < cnt; i += 256) {
        float lg = logits[beg + i];
        if (fits) slog[i] = lg;
        lmax = fmaxf(lmax, lg);
    }
    #pragma unroll
    for (int off = 32; off > 0; off >>= 1)
        lmax = fmaxf(lmax, __shfl_down(lmax, off));
    if ((t & 63) == 0) sred[t >> 6] = lmax;
    __syncthreads();
    if (t == 0) sbc[0] = fmaxf(fmaxf(sred[0], sred[1]), fmaxf(sred[2], sred[3]));
    __syncthreads();
    float gm = sbc[0];

    float lsum = 0.f;
    for (int i = t; i < cnt; i += 256) {
        float lg = fits ? slog[i] : logits[beg + i];
        float e = expf(lg - gm);
        if (fits) slog[i] = e;
        lsum += e;
    }
    #pragma unroll
    for (int off = 32; off > 0; off >>= 1)
        lsum += __shfl_down(lsum, off);
    __syncthreads();
    if ((t & 63) == 0) sred[t >> 6] = lsum;
    __syncthreads();
    if (t == 0) sbc[1] = (sred[0] + sred[1]) + (sred[2] + sred[3]);
    __syncthreads();
    float inv = 1.0f / sbc[1];

    for (int i = t; i < cnt; i += 256) {
        float e = fits ? slog[i] : expf(logits[beg + i] - gm);
        out[beg + i] = e * inv;
    }
}

// ---------- launch ----------
extern "C" void kernel_launch(void* const* d_in, const int* in_sizes, int n_in,
                              void* d_out, int out_size, void* d_ws, size_t ws_size,
                              hipStream_t stream) {
    const float* x    = (const float*)d_in[0];
    const int*   ei   = (const int*)d_in[1];
    const int*   srcI = ei;
    const int*   dstI = ei + NE;
    const int*   batch = (const int*)d_in[2];

    const float* P[29];
    for (int i = 0; i < 29; i++) P[i] = (const float*)d_in[i];
    const float* Wlin = P[27];
    const float* blin = P[28];

    unsigned short* xh  = (unsigned short*)d_ws;       // N x 128 bf16
    unsigned short* z1h = xh + (size_t)NN * 128;       // N x 64 bf16
    unsigned short* z2h = z1h + (size_t)NN * 64;       // N x 32 bf16
    float* logits = (float*)(z2h + (size_t)NN * 32);   // N
    int* gstart = (int*)(logits + NN);                 // NG+1
    int* rowptr = gstart + NG + 1;                     // N+1
    int* cnt1   = rowptr + NN + 1;                     // CB x NBK
    uintptr_t tal = ((uintptr_t)(cnt1 + CB * NBK) + 15) & ~(uintptr_t)15;
    unsigned* tmp = (unsigned*)tal;                    // NE packed (bucket-major)
    int* esrc   = (int*)(tmp + NE);                    // E
    uintptr_t pal = ((uintptr_t)(esrc + NE) + 255) & ~(uintptr_t)255;
    unsigned short* aggh  = (unsigned short*)pal;      // N x 128 bf16
    unsigned short* W1t   = aggh + (size_t)NN * 128;   // 128x128 bf16 [n][k]
    unsigned short* W2t   = W1t + 16384;               // 128x128 bf16 [n][k]
    unsigned short* W3t   = W2t + 16384;               // 64x128 bf16 [n][k]
    unsigned short* W21t  = W3t + 8192;                // 64x64 bf16 [n][k]
    unsigned short* W12t  = W21t + 4096;               // 32x64 bf16 [n][k]
    unsigned short* agg1h = W12t + 2048;               // N x 64 bf16
    unsigned short* agg2h = agg1h + (size_t)NN * 64;   // N x 32 bf16
    float* outp = (float*)d_out;

    const int TB = 256;

    // CSR build: zero global atomics (LDS-histogram bucket sort, per-block scans)
    conv_count<<<(N4 + TB - 1) / TB, TB, 0, stream>>>(
        (const float4*)x, (ushort4*)xh, (const int4*)dstI, cnt1);
    scatter1<<<CB, 256, 0, stream>>>(
        (const int4*)srcI, (const int4*)dstI, cnt1, tmp);
    bucket_build<<<NBK, 256, 0, stream>>>(tmp, cnt1, batch, rowptr, gstart, esrc,
        P[3], P[5], P[11], P[13], P[19], W1t, W2t, W3t, W21t, W12t);

    const int GB   = (NN + 3) / 4;     // gathers: 1 wave/node
    const int FB64 = (NN + 63) / 64;
    const int FB32 = (NN + 31) / 32;

    gather_L0<<<GB, 256, 0, stream>>>(xh, esrc, rowptr, aggh);
    gemm_L0<<<FB64, 256, 0, stream>>>(aggh, z1h, W1t, W2t, W3t,
        P[4], P[6], P[7], P[8], P[9], P[10]);
    gather_L1<<<GB, 256, 0, stream>>>(z1h, esrc, rowptr, P[12], agg1h);
    gemm_L1<<<FB64, 256, 0, stream>>>(agg1h, z2h, W21t, W12t,
        P[14], P[15], P[16], P[17], P[18]);
    gather_L2<<<GB, 256, 0, stream>>>(z2h, esrc, rowptr, P[20], agg2h);
    gemm_L2<<<FB32, 256, 0, stream>>>(agg2h, logits,
        P[21], P[22], P[23], P[24], P[25], P[26], Wlin, blin);

    seg_softmax<<<NG, 256, 0, stream>>>(logits, gstart, outp);
}